// Round 1
// 1711.157 us; speedup vs baseline: 1.0679x; 1.0679x over previous
//
#include <hip/hip_runtime.h>
#include <hip/hip_bf16.h>
#include <stdint.h>

// ChimeraBlock (Mamba2-style) for MI355X.
// Round 5: scan_ssd occupancy + staging rework:
//   - LDS 57KB -> 38KB (drop Bs/Cs; B/C frags loaded direct from global (L2-hot),
//     Ts built from the thread's own B row) -> 4 blocks/CU (__launch_bounds__(256,4))
//   - XOR column swizzle on XT/Ts scatter-transpose writes -> conflict-free banks
//   - HT written as packed bf16x2 (half the stores)
//   - y epilogue staged through LDS -> 2x16B coalesced stores (was 16x2B scatter)
//   - group loop un-runtime'd (two inlined calls, static Hst0/Hst1 refs)

#define D_MODEL 768
#define D_INNER 1536
#define NH 24
#define D_IN_PROJ 3424      // 2*1536 + 256 + 96
#define CONV_DIM 1792       // 1536 + 256
#define NDT 96
#define LSEQ 1024

typedef __bf16 bf16x8 __attribute__((ext_vector_type(8)));
typedef float f32x4 __attribute__((ext_vector_type(4)));

// ---------------- f32 -> bf16 convert (x4 vectorized) ----------------
__global__ void cvt_kernel(const float* __restrict__ src, __hip_bfloat16* __restrict__ dst, int n4) {
    int i = blockIdx.x * 256 + threadIdx.x;
    if (i < n4) {
        float4 v = ((const float4*)src)[i];
        __hip_bfloat162 lo, hi;
        lo.x = __float2bfloat16(v.x); lo.y = __float2bfloat16(v.y);
        hi.x = __float2bfloat16(v.z); hi.y = __float2bfloat16(v.w);
        ((__hip_bfloat162*)dst)[2*i]   = lo;
        ((__hip_bfloat162*)dst)[2*i+1] = hi;
    }
}

// ---------------- bf16 NT GEMM: C[m,n] = sum_k A[m,k] * Bt[n,k] ----------------
__device__ __forceinline__ void gl_lds16(const __hip_bfloat16* g, __hip_bfloat16* l) {
    __builtin_amdgcn_global_load_lds(
        (const __attribute__((address_space(1))) void*)g,
        (__attribute__((address_space(3))) void*)l, 16, 0, 0);
}

// MODE 0: f32 out (OutF, width N).  MODE 1: split out -> Z(1536) | XBC(1792) | DT(96 f32)
template<int MODE>
__global__ __launch_bounds__(256) void gemm_bt(
    const __hip_bfloat16* __restrict__ A,   // M x K
    const __hip_bfloat16* __restrict__ Bt,  // N x K
    float* __restrict__ OutF,
    __hip_bfloat16* __restrict__ Z, __hip_bfloat16* __restrict__ XBC, float* __restrict__ DT,
    int M, int N, int K)
{
    __shared__ __hip_bfloat16 As[128*32];
    __shared__ __hip_bfloat16 Bs[128*32];
    const int tid  = threadIdx.x;
    const int wave = tid >> 6, lane = tid & 63;
    const int bm = blockIdx.x * 128, bn = blockIdx.y * 128;
    const int wm = (wave >> 1) * 64, wn = (wave & 1) * 64;
    f32x4 acc[4][4] = {};
    const int lrow = lane >> 2;
    const int lcol = (lane & 3) * 8;
    const int fr = lane & 15, fk = (lane >> 4) * 8;
    const int ktiles = K >> 5;
    for (int kt = 0; kt < ktiles; ++kt) {
        const int kofs = kt * 32;
        #pragma unroll
        for (int cc = 0; cc < 2; ++cc) {
            int r = (wave*2 + cc)*16 + lrow;
            gl_lds16(A + (size_t)(bm + r)*K + kofs + lcol, &As[r*32 + lcol]);
            int gn = bn + r; if (gn > N-1) gn = N-1;
            gl_lds16(Bt + (size_t)gn*K + kofs + lcol, &Bs[r*32 + lcol]);
        }
        __syncthreads();
        bf16x8 af[4], bfr[4];
        #pragma unroll
        for (int i = 0; i < 4; ++i)
            af[i] = *reinterpret_cast<const bf16x8*>(&As[(wm + i*16 + fr)*32 + fk]);
        #pragma unroll
        for (int j = 0; j < 4; ++j)
            bfr[j] = *reinterpret_cast<const bf16x8*>(&Bs[(wn + j*16 + fr)*32 + fk]);
        #pragma unroll
        for (int i = 0; i < 4; ++i)
            #pragma unroll
            for (int j = 0; j < 4; ++j)
                acc[i][j] = __builtin_amdgcn_mfma_f32_16x16x32_bf16(af[i], bfr[j], acc[i][j], 0, 0, 0);
        __syncthreads();
    }
    const int er = (lane >> 4) * 4;
    const int ec = lane & 15;
    #pragma unroll
    for (int i = 0; i < 4; ++i) {
        #pragma unroll
        for (int j = 0; j < 4; ++j) {
            #pragma unroll
            for (int r = 0; r < 4; ++r) {
                int row = bm + wm + i*16 + er + r;
                int col = bn + wn + j*16 + ec;
                if (col < N) {
                    float v = acc[i][j][r];
                    if (MODE == 0) {
                        OutF[(size_t)row*N + col] = v;
                    } else {
                        if (col < D_INNER)
                            Z[(size_t)row*D_INNER + col] = __float2bfloat16(v);
                        else if (col < 3328)
                            XBC[(size_t)row*CONV_DIM + (col - D_INNER)] = __float2bfloat16(v);
                        else
                            DT[(size_t)row*NDT + (col - 3328)] = v;
                    }
                }
            }
        }
    }
}

// ---------------- depthwise 3x3 conv + bias + SiLU ----------------
__global__ __launch_bounds__(256) void conv_kernel(
    const __hip_bfloat16* __restrict__ xbc, // (R, 1792)
    const float* __restrict__ cw,           // (1792, 9)
    const float* __restrict__ cb,           // (1792)
    __hip_bfloat16* __restrict__ out)       // (R, 1792)
{
    size_t idx = (size_t)blockIdx.x * 256 + threadIdx.x;
    int c = (int)(idx % CONV_DIM);
    size_t bp = idx / CONV_DIM;
    int pix = (int)(bp % LSEQ);
    int b = (int)(bp / LSEQ);
    int y = pix >> 5, x = pix & 31;
    float acc = cb[c];
    const float* w = cw + c*9;
    #pragma unroll
    for (int dy = -1; dy <= 1; ++dy) {
        int yy = y + dy; if (yy < 0 || yy > 31) continue;
        #pragma unroll
        for (int dx = -1; dx <= 1; ++dx) {
            int xx = x + dx; if (xx < 0 || xx > 31) continue;
            size_t r = ((size_t)b*LSEQ + yy*32 + xx)*CONV_DIM + c;
            acc += w[(dy+1)*3 + (dx+1)] * __bfloat162float(xbc[r]);
        }
    }
    float s = acc / (1.f + __expf(-acc));
    out[idx] = __float2bfloat16(s);
}

// ---------------- chunked SSD scan on MFMA ----------------
// Block = (b, h, dir), 256 threads (4 waves).  LDS rows stride PADW=72 elems.
// Column XOR swizzle (bits 3..5) keeps bf16x8 frags contiguous & 16B aligned
// while spreading the 4 scol-groups of the scatter-transpose across banks.
#define PADW 72
__device__ __forceinline__ f32x4 mfma16(bf16x8 a, bf16x8 b, f32x4 c) {
    return __builtin_amdgcn_mfma_f32_16x16x32_bf16(a, b, c, 0, 0, 0);
}

__global__ __launch_bounds__(256, 4) void scan_ssd(
    const __bf16* __restrict__ conv,   // (R, 1792): x | B(2x64) | C(2x64)
    const float* __restrict__ dtraw,   // (R, 96): [k][h], k = 2g + dir
    __bf16* __restrict__ yf,           // (R, 1536)
    __bf16* __restrict__ yr)           // (R, 1536)
{
    const int tid = threadIdx.x;
    const int w = tid >> 6, lane = tid & 63;
    const int b = blockIdx.x, h = blockIdx.y, dir = blockIdx.z;
    __bf16* yout = dir ? yr : yf;
    const size_t base = (size_t)b * LSEQ;

    __shared__ __align__(16) __bf16 XT[64*PADW];  // X^T: [p][tau ^ swz(p)]
    __shared__ __align__(16) __bf16 Gs[64*PADW];  // G':  [tau][s]
    __shared__ __align__(16) __bf16 Ts[64*PADW];  // (wB)^T: [n][s ^ swz(n)]; reused as y-stage [tau][p]
    __shared__ __align__(16) __bf16 HT[64*PADW];  // H^T: [p][n]
    __shared__ float Sarr[2][64], Dtar[2][64], Warr[2][64], Earr[2][64];

    f32x4 Hst0[4] = {}, Hst1[4] = {};      // state H[n][p] per group: n-slab = wave

    const int srow = tid >> 2;             // staging: physical row offset 0..63
    const int scol = (tid & 3) * 16;       // staging: 16-element column group
    const int fr = lane & 15, fkq = (lane >> 4) * 8;   // frag row / k base
    const int er = (lane >> 4) * 4, ec = lane & 15;    // C/D row base / col

    #pragma unroll 1
    for (int c = 0; c < 16; ++c) {
        const int rA = dir ? (LSEQ - (c+1)*64) : c*64;   // physical start row in image
        __syncthreads();   // (z) guard all LDS overwrites vs prev chunk reads
        {   // stage X^T (swizzled scatter-transpose) ; compute S arrays (waves 0,1)
            const int q = srow; const int tau = dir ? 63 - q : q;
            const __bf16* src = conv + (base + rA + q) * (size_t)CONV_DIM + h*64 + scol;
            bf16x8 v0 = *(const bf16x8*)(src);
            bf16x8 v1 = *(const bf16x8*)(src + 8);
            #pragma unroll
            for (int i = 0; i < 8; ++i) {
                const int p = scol + i;
                XT[p*PADW + (tau ^ (((p >> 3) & 7) << 3))] = v0[i];
            }
            #pragma unroll
            for (int i = 0; i < 8; ++i) {
                const int p = scol + 8 + i;
                XT[p*PADW + (tau ^ (((p >> 3) & 7) << 3))] = v1[i];
            }
            if (tid < 128) {
                const int g = tid >> 6;
                const int t2 = lane;                       // scan position
                const int k = 2*g + dir;
                const int rowg = rA + (dir ? 63 - t2 : t2);
                float draw = dtraw[(base + rowg)*NDT + k*24 + h];
                float e = __expf(draw);
                float dts = __logf(1.f + e);               // softplus
                float s = dts;
                #pragma unroll
                for (int off = 1; off < 64; off <<= 1) {   // inclusive prefix sum
                    float v = __shfl_up(s, off, 64);
                    if (lane >= off) s += v;
                }
                float stot = __shfl(s, 63, 64);
                Sarr[g][t2] = s;
                Dtar[g][t2] = dts;
                Warr[g][t2] = __expf(s - stot) * dts;
                Earr[g][t2] = __expf(-s);
            }
        }
        __syncthreads();   // (a)
        f32x4 Yacc[4] = {};

        auto group = [&](const int g, f32x4 (&Hst)[4]) {
            {   // Ts = (w_s * B_s)^T from this thread's own B row (s' = logical idx)
                const int sl = dir ? 63 - srow : srow;
                const __bf16* bp = conv + (base + rA + srow) * (size_t)CONV_DIM + 1536 + g*64;
                bf16x8 b0 = *(const bf16x8*)(bp + scol);
                bf16x8 b1 = *(const bf16x8*)(bp + scol + 8);
                float ws = Warr[g][sl];
                #pragma unroll
                for (int i = 0; i < 8; ++i) {
                    const int n = scol + i;
                    Ts[n*PADW + (sl ^ (((n >> 3) & 7) << 3))] = (__bf16)((float)b0[i] * ws);
                }
                #pragma unroll
                for (int i = 0; i < 8; ++i) {
                    const int n = scol + 8 + i;
                    Ts[n*PADW + (sl ^ (((n >> 3) & 7) << 3))] = (__bf16)((float)b1[i] * ws);
                }
            }
            // C frags direct from global (rows map 1:1 to lanes, L2-hot)
            const int rn = w*16 + fr;
            const int qf = dir ? 63 - rn : rn;
            const __bf16* cp = conv + (base + rA + qf) * (size_t)CONV_DIM + 1664 + g*64;
            bf16x8 cfr0 = *(const bf16x8*)(cp + fkq);
            bf16x8 cfr1 = *(const bf16x8*)(cp + 32 + fkq);
            // G = C B^T  (K = n = 64), B frags direct from global
            f32x4 Gacc[4] = {};
            #pragma unroll
            for (int s4 = 0; s4 < 4; ++s4) {
                const int s = s4*16 + fr;
                const int q = dir ? 63 - s : s;
                const __bf16* bp2 = conv + (base + rA + q) * (size_t)CONV_DIM + 1536 + g*64;
                bf16x8 bb0 = *(const bf16x8*)(bp2 + fkq);
                bf16x8 bb1 = *(const bf16x8*)(bp2 + 32 + fkq);
                Gacc[s4] = mfma16(cfr0, bb0, Gacc[s4]);
                Gacc[s4] = mfma16(cfr1, bb1, Gacc[s4]);
            }
            // write H^T (h_init, unscaled) from regs, packed bf16x2
            #pragma unroll
            for (int t4 = 0; t4 < 4; ++t4) {
                const int p = t4*16 + ec;
                #pragma unroll
                for (int j = 0; j < 2; ++j) {
                    const int n = w*16 + er + 2*j;
                    __hip_bfloat162 pr;
                    pr.x = __float2bfloat16(Hst[t4][2*j]);
                    pr.y = __float2bfloat16(Hst[t4][2*j+1]);
                    *(__hip_bfloat162*)&HT[p*PADW + n] = pr;
                }
            }
            // scale H regs by chunk decay
            const float e63 = Earr[g][63];
            #pragma unroll
            for (int t4 = 0; t4 < 4; ++t4)
                #pragma unroll
                for (int rr = 0; rr < 4; ++rr) Hst[t4][rr] *= e63;
            // mask G -> Gs (bf16): M[tau,s] = exp(S_s - S_tau)*dt_s for tau>=s
            #pragma unroll
            for (int s4 = 0; s4 < 4; ++s4) {
                const int s = s4*16 + ec;
                const float Ss = Sarr[g][s], dts = Dtar[g][s];
                #pragma unroll
                for (int rr = 0; rr < 4; ++rr) {
                    const int tau = w*16 + er + rr;
                    float m = (tau >= s) ? __expf(Ss - Sarr[g][tau]) * dts : 0.f;
                    Gs[tau*PADW + s] = (__bf16)(Gacc[s4][rr] * m);
                }
            }
            __syncthreads();   // (c)
            // Y += G' X + (E*C) H ; H += (wB)^T X
            bf16x8 ga0 = *(const bf16x8*)&Gs[rn*PADW + fkq];
            bf16x8 ga1 = *(const bf16x8*)&Gs[rn*PADW + 32 + fkq];
            const float esc = Earr[g][rn];
            bf16x8 ca0, ca1;
            #pragma unroll
            for (int i = 0; i < 8; ++i) {
                ca0[i] = (__bf16)((float)cfr0[i] * esc);
                ca1[i] = (__bf16)((float)cfr1[i] * esc);
            }
            const int Sn = ((rn >> 3) & 7) << 3;
            bf16x8 ta0 = *(const bf16x8*)&Ts[rn*PADW + (fkq ^ Sn)];
            bf16x8 ta1 = *(const bf16x8*)&Ts[rn*PADW + ((32 + fkq) ^ Sn)];
            #pragma unroll
            for (int p4 = 0; p4 < 4; ++p4) {
                const int p = p4*16 + fr;
                const int Sp = ((p >> 3) & 7) << 3;
                bf16x8 x0 = *(const bf16x8*)&XT[p*PADW + (fkq ^ Sp)];
                bf16x8 x1 = *(const bf16x8*)&XT[p*PADW + ((32 + fkq) ^ Sp)];
                bf16x8 h0 = *(const bf16x8*)&HT[p*PADW + fkq];
                bf16x8 h1 = *(const bf16x8*)&HT[p*PADW + 32 + fkq];
                Yacc[p4] = mfma16(ga0, x0, Yacc[p4]);
                Yacc[p4] = mfma16(ga1, x1, Yacc[p4]);
                Yacc[p4] = mfma16(ca0, h0, Yacc[p4]);
                Yacc[p4] = mfma16(ca1, h1, Yacc[p4]);
                Hst[p4] = mfma16(ta0, x0, Hst[p4]);
                Hst[p4] = mfma16(ta1, x1, Hst[p4]);
            }
        };

        group(0, Hst0);
        __syncthreads();   // WAR: g1's Ts/Gs/HT writes vs g0's Y-phase reads
        group(1, Hst1);

        __syncthreads();   // (d) guard y-stage overwrite of Ts vs g1 Y-phase reads
        #pragma unroll
        for (int p4 = 0; p4 < 4; ++p4)
            #pragma unroll
            for (int rr = 0; rr < 4; ++rr) {
                const int tau = w*16 + er + rr;
                Ts[tau*PADW + p4*16 + ec] = (__bf16)Yacc[p4][rr];
            }
        __syncthreads();   // (e)
        {   // coalesced y store: 2 x 16B per thread
            const int rowp = rA + (dir ? 63 - srow : srow);
            bf16x8 y0 = *(const bf16x8*)&Ts[srow*PADW + scol];
            bf16x8 y1 = *(const bf16x8*)&Ts[srow*PADW + scol + 8];
            __bf16* dst = yout + (base + rowp)*(size_t)D_INNER + h*64 + scol;
            *(bf16x8*)dst = y0;
            *(bf16x8*)(dst + 8) = y1;
        }
    }
}

// ---------------- gate (y * silu(z)) + RMSNorm + norm_w, bf16 out ----------------
__global__ __launch_bounds__(256) void gate_kernel(
    const __hip_bfloat16* __restrict__ yf, const __hip_bfloat16* __restrict__ yr,
    const __hip_bfloat16* __restrict__ z, const float* __restrict__ norm_w,
    __hip_bfloat16* __restrict__ yn)
{
    const int row = blockIdx.x, tid = threadIdx.x;
    const size_t ybase = (size_t)row * D_INNER;
    float yg[6]; float ss = 0.f;
    #pragma unroll
    for (int k = 0; k < 6; ++k) {
        int j = tid + k*256;
        float yv = __bfloat162float(yf[ybase+j]) + __bfloat162float(yr[ybase+j]);
        float zz = __bfloat162float(z[ybase+j]);
        float g  = yv * (zz / (1.f + __expf(-zz)));
        yg[k] = g; ss += g*g;
    }
    #pragma unroll
    for (int off = 32; off > 0; off >>= 1) ss += __shfl_down(ss, off, 64);
    __shared__ float red[4];
    if ((tid & 63) == 0) red[tid >> 6] = ss;
    __syncthreads();
    float total = red[0] + red[1] + red[2] + red[3];
    float rn = rsqrtf(total * (1.f/1536.f) + 1e-5f);
    #pragma unroll
    for (int k = 0; k < 6; ++k) {
        int j = tid + k*256;
        yn[ybase+j] = __float2bfloat16(yg[k] * rn * norm_w[j]);
    }
}

// ---------------- launch ----------------
extern "C" void kernel_launch(void* const* d_in, const int* in_sizes, int n_in,
                              void* d_out, int out_size, void* d_ws, size_t ws_size,
                              hipStream_t stream) {
    const float* u      = (const float*)d_in[0];
    const float* w_in   = (const float*)d_in[1];
    const float* conv_w = (const float*)d_in[2];
    const float* conv_b = (const float*)d_in[3];
    const float* norm_w = (const float*)d_in[4];
    const float* w_out  = (const float*)d_in[5];
    (void)in_sizes; (void)n_in; (void)out_size;

    char* ws = (char*)d_ws;
    const size_t nWin  = (size_t)D_IN_PROJ * D_MODEL;
    const size_t nWout = (size_t)D_MODEL * D_INNER;
    __hip_bfloat16* win_bf  = (__hip_bfloat16*)ws;
    __hip_bfloat16* wout_bf = (__hip_bfloat16*)(ws + nWin*2);
    const size_t wbytes = nWin*2 + nWout*2;
    char* arena = ws + wbytes;

    const size_t perRow = 10624;
    int CB = 32;
    while (CB > 1 && wbytes + perRow*(size_t)CB*1024 > ws_size) CB >>= 1;
    const int nchunks = 32 / CB;
    const size_t R = (size_t)CB * 1024;

    __hip_bfloat16* segA = (__hip_bfloat16*)arena;                 // u_bf, then yf
    char* pC = arena + R*3072;
    char* pD = pC + R*3584;
    char* pE = pD + R*384;
    __hip_bfloat16* xbc_bf  = (__hip_bfloat16*)pC;                 // then yr
    __hip_bfloat16* yr_bf   = (__hip_bfloat16*)pC;
    float*          dt_f32  = (float*)pD;
    __hip_bfloat16* conv_bf = (__hip_bfloat16*)pE;                 // then yn
    __hip_bfloat16* yn_bf   = (__hip_bfloat16*)pE;
    __hip_bfloat16* u_bf    = segA;
    __hip_bfloat16* yf_bf   = segA;

    cvt_kernel<<<(int)((nWin/4 + 255)/256), 256, 0, stream>>>(w_in, win_bf, (int)(nWin/4));
    cvt_kernel<<<(int)((nWout/4 + 255)/256), 256, 0, stream>>>(w_out, wout_bf, (int)(nWout/4));

    for (int c = 0; c < nchunks; ++c) {
        const float* u_c = u + (size_t)c * R * D_MODEL;
        __hip_bfloat16* z_bf = (__hip_bfloat16*)((char*)d_out + (size_t)c * R * 3072);
        float* out_c = (float*)d_out + (size_t)c * R * D_MODEL;

        const size_t nUc4 = R * D_MODEL / 4;
        cvt_kernel<<<(int)((nUc4 + 255)/256), 256, 0, stream>>>(u_c, u_bf, (int)nUc4);

        gemm_bt<1><<<dim3((int)(R/128), (D_IN_PROJ + 127)/128), 256, 0, stream>>>(
            u_bf, win_bf, nullptr, z_bf, xbc_bf, dt_f32, (int)R, D_IN_PROJ, D_MODEL);

        conv_kernel<<<(int)((R*CONV_DIM)/256), 256, 0, stream>>>(xbc_bf, conv_w, conv_b, conv_bf);

        scan_ssd<<<dim3(CB, NH, 2), 256, 0, stream>>>(
            (const __bf16*)conv_bf, dt_f32, (__bf16*)yf_bf, (__bf16*)yr_bf);

        gate_kernel<<<(int)R, 256, 0, stream>>>(yf_bf, yr_bf, z_bf, norm_w, yn_bf);

        gemm_bt<0><<<dim3((int)(R/128), D_MODEL/128), 256, 0, stream>>>(
            yn_bf, wout_bf, out_c, nullptr, nullptr, nullptr, (int)R, D_MODEL, D_INNER);
    }
}

// Round 2
// 1333.964 us; speedup vs baseline: 1.3699x; 1.2828x over previous
//
#include <hip/hip_runtime.h>
#include <hip/hip_bf16.h>
#include <stdint.h>

// ChimeraBlock (Mamba2-style) for MI355X.
// Round 6: conv_kernel vectorized 8-channels-per-thread:
//   - was: 1 thread = 1 (pixel, channel), 9 x 2B scalar bf16 loads (request-bound,
//     HBM 6%, VALU 28%, 572us)
//   - now: 1 thread = 1 (pixel, 8-channel group), 9 x 16B bf16x8 loads + repacked
//     (9,1792) f32 weights (two float4/tap, L1-hot) -> 8x fewer memory requests
//   - conv_w repacked once per run by repack_w

#define D_MODEL 768
#define D_INNER 1536
#define NH 24
#define D_IN_PROJ 3424      // 2*1536 + 256 + 96
#define CONV_DIM 1792       // 1536 + 256
#define NDT 96
#define LSEQ 1024

typedef __bf16 bf16x8 __attribute__((ext_vector_type(8)));
typedef float f32x4 __attribute__((ext_vector_type(4)));

// ---------------- f32 -> bf16 convert (x4 vectorized) ----------------
__global__ void cvt_kernel(const float* __restrict__ src, __hip_bfloat16* __restrict__ dst, int n4) {
    int i = blockIdx.x * 256 + threadIdx.x;
    if (i < n4) {
        float4 v = ((const float4*)src)[i];
        __hip_bfloat162 lo, hi;
        lo.x = __float2bfloat16(v.x); lo.y = __float2bfloat16(v.y);
        hi.x = __float2bfloat16(v.z); hi.y = __float2bfloat16(v.w);
        ((__hip_bfloat162*)dst)[2*i]   = lo;
        ((__hip_bfloat162*)dst)[2*i+1] = hi;
    }
}

// ---------------- conv weight repack: (1792, 9) -> (9, 1792) ----------------
__global__ void repack_w(const float* __restrict__ cw, float* __restrict__ wT) {
    int i = blockIdx.x * 256 + threadIdx.x;
    if (i < CONV_DIM * 9) {
        int c = i / 9, t = i % 9;
        wT[t * CONV_DIM + c] = cw[i];
    }
}

// ---------------- bf16 NT GEMM: C[m,n] = sum_k A[m,k] * Bt[n,k] ----------------
__device__ __forceinline__ void gl_lds16(const __hip_bfloat16* g, __hip_bfloat16* l) {
    __builtin_amdgcn_global_load_lds(
        (const __attribute__((address_space(1))) void*)g,
        (__attribute__((address_space(3))) void*)l, 16, 0, 0);
}

// MODE 0: f32 out (OutF, width N).  MODE 1: split out -> Z(1536) | XBC(1792) | DT(96 f32)
template<int MODE>
__global__ __launch_bounds__(256) void gemm_bt(
    const __hip_bfloat16* __restrict__ A,   // M x K
    const __hip_bfloat16* __restrict__ Bt,  // N x K
    float* __restrict__ OutF,
    __hip_bfloat16* __restrict__ Z, __hip_bfloat16* __restrict__ XBC, float* __restrict__ DT,
    int M, int N, int K)
{
    __shared__ __hip_bfloat16 As[128*32];
    __shared__ __hip_bfloat16 Bs[128*32];
    const int tid  = threadIdx.x;
    const int wave = tid >> 6, lane = tid & 63;
    const int bm = blockIdx.x * 128, bn = blockIdx.y * 128;
    const int wm = (wave >> 1) * 64, wn = (wave & 1) * 64;
    f32x4 acc[4][4] = {};
    const int lrow = lane >> 2;
    const int lcol = (lane & 3) * 8;
    const int fr = lane & 15, fk = (lane >> 4) * 8;
    const int ktiles = K >> 5;
    for (int kt = 0; kt < ktiles; ++kt) {
        const int kofs = kt * 32;
        #pragma unroll
        for (int cc = 0; cc < 2; ++cc) {
            int r = (wave*2 + cc)*16 + lrow;
            gl_lds16(A + (size_t)(bm + r)*K + kofs + lcol, &As[r*32 + lcol]);
            int gn = bn + r; if (gn > N-1) gn = N-1;
            gl_lds16(Bt + (size_t)gn*K + kofs + lcol, &Bs[r*32 + lcol]);
        }
        __syncthreads();
        bf16x8 af[4], bfr[4];
        #pragma unroll
        for (int i = 0; i < 4; ++i)
            af[i] = *reinterpret_cast<const bf16x8*>(&As[(wm + i*16 + fr)*32 + fk]);
        #pragma unroll
        for (int j = 0; j < 4; ++j)
            bfr[j] = *reinterpret_cast<const bf16x8*>(&Bs[(wn + j*16 + fr)*32 + fk]);
        #pragma unroll
        for (int i = 0; i < 4; ++i)
            #pragma unroll
            for (int j = 0; j < 4; ++j)
                acc[i][j] = __builtin_amdgcn_mfma_f32_16x16x32_bf16(af[i], bfr[j], acc[i][j], 0, 0, 0);
        __syncthreads();
    }
    const int er = (lane >> 4) * 4;
    const int ec = lane & 15;
    #pragma unroll
    for (int i = 0; i < 4; ++i) {
        #pragma unroll
        for (int j = 0; j < 4; ++j) {
            #pragma unroll
            for (int r = 0; r < 4; ++r) {
                int row = bm + wm + i*16 + er + r;
                int col = bn + wn + j*16 + ec;
                if (col < N) {
                    float v = acc[i][j][r];
                    if (MODE == 0) {
                        OutF[(size_t)row*N + col] = v;
                    } else {
                        if (col < D_INNER)
                            Z[(size_t)row*D_INNER + col] = __float2bfloat16(v);
                        else if (col < 3328)
                            XBC[(size_t)row*CONV_DIM + (col - D_INNER)] = __float2bfloat16(v);
                        else
                            DT[(size_t)row*NDT + (col - 3328)] = v;
                    }
                }
            }
        }
    }
}

// ---------------- depthwise 3x3 conv + bias + SiLU, 8 ch/thread ----------------
__global__ __launch_bounds__(256) void conv_kernel(
    const __hip_bfloat16* __restrict__ xbc, // (R, 1792)
    const float* __restrict__ wT,           // (9, 1792) repacked
    const float* __restrict__ cb,           // (1792)
    __hip_bfloat16* __restrict__ out)       // (R, 1792)
{
    size_t idx = (size_t)blockIdx.x * 256 + threadIdx.x;   // R * 224 threads
    const int cg = (int)(idx % (CONV_DIM / 8));
    const int c = cg * 8;
    size_t bp = idx / (CONV_DIM / 8);
    const int pix = (int)(bp % LSEQ);
    const int b = (int)(bp / LSEQ);
    const int y = pix >> 5, x = pix & 31;
    float acc[8];
    {
        float4 c0 = *(const float4*)(cb + c);
        float4 c1 = *(const float4*)(cb + c + 4);
        acc[0]=c0.x; acc[1]=c0.y; acc[2]=c0.z; acc[3]=c0.w;
        acc[4]=c1.x; acc[5]=c1.y; acc[6]=c1.z; acc[7]=c1.w;
    }
    const size_t rowbase = (size_t)b * LSEQ;
    #pragma unroll
    for (int dy = -1; dy <= 1; ++dy) {
        int yy = y + dy; if (yy < 0 || yy > 31) continue;
        #pragma unroll
        for (int dx = -1; dx <= 1; ++dx) {
            int xx = x + dx; if (xx < 0 || xx > 31) continue;
            const int t = (dy+1)*3 + (dx+1);
            bf16x8 v = *(const bf16x8*)(xbc + (rowbase + yy*32 + xx)*(size_t)CONV_DIM + c);
            float4 w0 = *(const float4*)(wT + t*CONV_DIM + c);
            float4 w1 = *(const float4*)(wT + t*CONV_DIM + c + 4);
            acc[0] += w0.x * (float)v[0];
            acc[1] += w0.y * (float)v[1];
            acc[2] += w0.z * (float)v[2];
            acc[3] += w0.w * (float)v[3];
            acc[4] += w1.x * (float)v[4];
            acc[5] += w1.y * (float)v[5];
            acc[6] += w1.z * (float)v[6];
            acc[7] += w1.w * (float)v[7];
        }
    }
    bf16x8 o;
    #pragma unroll
    for (int i = 0; i < 8; ++i) {
        float s = acc[i] / (1.f + __expf(-acc[i]));
        o[i] = (__bf16)s;
    }
    *(bf16x8*)(out + (rowbase + pix)*(size_t)CONV_DIM + c) = o;
}

// ---------------- chunked SSD scan on MFMA ----------------
// Block = (b, h, dir), 256 threads (4 waves).  LDS rows stride PADW=72 elems.
// Column XOR swizzle (bits 3..5) keeps bf16x8 frags contiguous & 16B aligned
// while spreading the 4 scol-groups of the scatter-transpose across banks.
#define PADW 72
__device__ __forceinline__ f32x4 mfma16(bf16x8 a, bf16x8 b, f32x4 c) {
    return __builtin_amdgcn_mfma_f32_16x16x32_bf16(a, b, c, 0, 0, 0);
}

__global__ __launch_bounds__(256, 4) void scan_ssd(
    const __bf16* __restrict__ conv,   // (R, 1792): x | B(2x64) | C(2x64)
    const float* __restrict__ dtraw,   // (R, 96): [k][h], k = 2g + dir
    __bf16* __restrict__ yf,           // (R, 1536)
    __bf16* __restrict__ yr)           // (R, 1536)
{
    const int tid = threadIdx.x;
    const int w = tid >> 6, lane = tid & 63;
    const int b = blockIdx.x, h = blockIdx.y, dir = blockIdx.z;
    __bf16* yout = dir ? yr : yf;
    const size_t base = (size_t)b * LSEQ;

    __shared__ __align__(16) __bf16 XT[64*PADW];  // X^T: [p][tau ^ swz(p)]
    __shared__ __align__(16) __bf16 Gs[64*PADW];  // G':  [tau][s]
    __shared__ __align__(16) __bf16 Ts[64*PADW];  // (wB)^T: [n][s ^ swz(n)]; reused as y-stage [tau][p]
    __shared__ __align__(16) __bf16 HT[64*PADW];  // H^T: [p][n]
    __shared__ float Sarr[2][64], Dtar[2][64], Warr[2][64], Earr[2][64];

    f32x4 Hst0[4] = {}, Hst1[4] = {};      // state H[n][p] per group: n-slab = wave

    const int srow = tid >> 2;             // staging: physical row offset 0..63
    const int scol = (tid & 3) * 16;       // staging: 16-element column group
    const int fr = lane & 15, fkq = (lane >> 4) * 8;   // frag row / k base
    const int er = (lane >> 4) * 4, ec = lane & 15;    // C/D row base / col

    #pragma unroll 1
    for (int c = 0; c < 16; ++c) {
        const int rA = dir ? (LSEQ - (c+1)*64) : c*64;   // physical start row in image
        __syncthreads();   // (z) guard all LDS overwrites vs prev chunk reads
        {   // stage X^T (swizzled scatter-transpose) ; compute S arrays (waves 0,1)
            const int q = srow; const int tau = dir ? 63 - q : q;
            const __bf16* src = conv + (base + rA + q) * (size_t)CONV_DIM + h*64 + scol;
            bf16x8 v0 = *(const bf16x8*)(src);
            bf16x8 v1 = *(const bf16x8*)(src + 8);
            #pragma unroll
            for (int i = 0; i < 8; ++i) {
                const int p = scol + i;
                XT[p*PADW + (tau ^ (((p >> 3) & 7) << 3))] = v0[i];
            }
            #pragma unroll
            for (int i = 0; i < 8; ++i) {
                const int p = scol + 8 + i;
                XT[p*PADW + (tau ^ (((p >> 3) & 7) << 3))] = v1[i];
            }
            if (tid < 128) {
                const int g = tid >> 6;
                const int t2 = lane;                       // scan position
                const int k = 2*g + dir;
                const int rowg = rA + (dir ? 63 - t2 : t2);
                float draw = dtraw[(base + rowg)*NDT + k*24 + h];
                float e = __expf(draw);
                float dts = __logf(1.f + e);               // softplus
                float s = dts;
                #pragma unroll
                for (int off = 1; off < 64; off <<= 1) {   // inclusive prefix sum
                    float v = __shfl_up(s, off, 64);
                    if (lane >= off) s += v;
                }
                float stot = __shfl(s, 63, 64);
                Sarr[g][t2] = s;
                Dtar[g][t2] = dts;
                Warr[g][t2] = __expf(s - stot) * dts;
                Earr[g][t2] = __expf(-s);
            }
        }
        __syncthreads();   // (a)
        f32x4 Yacc[4] = {};

        auto group = [&](const int g, f32x4 (&Hst)[4]) {
            {   // Ts = (w_s * B_s)^T from this thread's own B row (s' = logical idx)
                const int sl = dir ? 63 - srow : srow;
                const __bf16* bp = conv + (base + rA + srow) * (size_t)CONV_DIM + 1536 + g*64;
                bf16x8 b0 = *(const bf16x8*)(bp + scol);
                bf16x8 b1 = *(const bf16x8*)(bp + scol + 8);
                float ws = Warr[g][sl];
                #pragma unroll
                for (int i = 0; i < 8; ++i) {
                    const int n = scol + i;
                    Ts[n*PADW + (sl ^ (((n >> 3) & 7) << 3))] = (__bf16)((float)b0[i] * ws);
                }
                #pragma unroll
                for (int i = 0; i < 8; ++i) {
                    const int n = scol + 8 + i;
                    Ts[n*PADW + (sl ^ (((n >> 3) & 7) << 3))] = (__bf16)((float)b1[i] * ws);
                }
            }
            // C frags direct from global (rows map 1:1 to lanes, L2-hot)
            const int rn = w*16 + fr;
            const int qf = dir ? 63 - rn : rn;
            const __bf16* cp = conv + (base + rA + qf) * (size_t)CONV_DIM + 1664 + g*64;
            bf16x8 cfr0 = *(const bf16x8*)(cp + fkq);
            bf16x8 cfr1 = *(const bf16x8*)(cp + 32 + fkq);
            // G = C B^T  (K = n = 64), B frags direct from global
            f32x4 Gacc[4] = {};
            #pragma unroll
            for (int s4 = 0; s4 < 4; ++s4) {
                const int s = s4*16 + fr;
                const int q = dir ? 63 - s : s;
                const __bf16* bp2 = conv + (base + rA + q) * (size_t)CONV_DIM + 1536 + g*64;
                bf16x8 bb0 = *(const bf16x8*)(bp2 + fkq);
                bf16x8 bb1 = *(const bf16x8*)(bp2 + 32 + fkq);
                Gacc[s4] = mfma16(cfr0, bb0, Gacc[s4]);
                Gacc[s4] = mfma16(cfr1, bb1, Gacc[s4]);
            }
            // write H^T (h_init, unscaled) from regs, packed bf16x2
            #pragma unroll
            for (int t4 = 0; t4 < 4; ++t4) {
                const int p = t4*16 + ec;
                #pragma unroll
                for (int j = 0; j < 2; ++j) {
                    const int n = w*16 + er + 2*j;
                    __hip_bfloat162 pr;
                    pr.x = __float2bfloat16(Hst[t4][2*j]);
                    pr.y = __float2bfloat16(Hst[t4][2*j+1]);
                    *(__hip_bfloat162*)&HT[p*PADW + n] = pr;
                }
            }
            // scale H regs by chunk decay
            const float e63 = Earr[g][63];
            #pragma unroll
            for (int t4 = 0; t4 < 4; ++t4)
                #pragma unroll
                for (int rr = 0; rr < 4; ++rr) Hst[t4][rr] *= e63;
            // mask G -> Gs (bf16): M[tau,s] = exp(S_s - S_tau)*dt_s for tau>=s
            #pragma unroll
            for (int s4 = 0; s4 < 4; ++s4) {
                const int s = s4*16 + ec;
                const float Ss = Sarr[g][s], dts = Dtar[g][s];
                #pragma unroll
                for (int rr = 0; rr < 4; ++rr) {
                    const int tau = w*16 + er + rr;
                    float m = (tau >= s) ? __expf(Ss - Sarr[g][tau]) * dts : 0.f;
                    Gs[tau*PADW + s] = (__bf16)(Gacc[s4][rr] * m);
                }
            }
            __syncthreads();   // (c)
            // Y += G' X + (E*C) H ; H += (wB)^T X
            bf16x8 ga0 = *(const bf16x8*)&Gs[rn*PADW + fkq];
            bf16x8 ga1 = *(const bf16x8*)&Gs[rn*PADW + 32 + fkq];
            const float esc = Earr[g][rn];
            bf16x8 ca0, ca1;
            #pragma unroll
            for (int i = 0; i < 8; ++i) {
                ca0[i] = (__bf16)((float)cfr0[i] * esc);
                ca1[i] = (__bf16)((float)cfr1[i] * esc);
            }
            const int Sn = ((rn >> 3) & 7) << 3;
            bf16x8 ta0 = *(const bf16x8*)&Ts[rn*PADW + (fkq ^ Sn)];
            bf16x8 ta1 = *(const bf16x8*)&Ts[rn*PADW + ((32 + fkq) ^ Sn)];
            #pragma unroll
            for (int p4 = 0; p4 < 4; ++p4) {
                const int p = p4*16 + fr;
                const int Sp = ((p >> 3) & 7) << 3;
                bf16x8 x0 = *(const bf16x8*)&XT[p*PADW + (fkq ^ Sp)];
                bf16x8 x1 = *(const bf16x8*)&XT[p*PADW + ((32 + fkq) ^ Sp)];
                bf16x8 h0 = *(const bf16x8*)&HT[p*PADW + fkq];
                bf16x8 h1 = *(const bf16x8*)&HT[p*PADW + 32 + fkq];
                Yacc[p4] = mfma16(ga0, x0, Yacc[p4]);
                Yacc[p4] = mfma16(ga1, x1, Yacc[p4]);
                Yacc[p4] = mfma16(ca0, h0, Yacc[p4]);
                Yacc[p4] = mfma16(ca1, h1, Yacc[p4]);
                Hst[p4] = mfma16(ta0, x0, Hst[p4]);
                Hst[p4] = mfma16(ta1, x1, Hst[p4]);
            }
        };

        group(0, Hst0);
        __syncthreads();   // WAR: g1's Ts/Gs/HT writes vs g0's Y-phase reads
        group(1, Hst1);

        __syncthreads();   // (d) guard y-stage overwrite of Ts vs g1 Y-phase reads
        #pragma unroll
        for (int p4 = 0; p4 < 4; ++p4)
            #pragma unroll
            for (int rr = 0; rr < 4; ++rr) {
                const int tau = w*16 + er + rr;
                Ts[tau*PADW + p4*16 + ec] = (__bf16)Yacc[p4][rr];
            }
        __syncthreads();   // (e)
        {   // coalesced y store: 2 x 16B per thread
            const int rowp = rA + (dir ? 63 - srow : srow);
            bf16x8 y0 = *(const bf16x8*)&Ts[srow*PADW + scol];
            bf16x8 y1 = *(const bf16x8*)&Ts[srow*PADW + scol + 8];
            __bf16* dst = yout + (base + rowp)*(size_t)D_INNER + h*64 + scol;
            *(bf16x8*)dst = y0;
            *(bf16x8*)(dst + 8) = y1;
        }
    }
}

// ---------------- gate (y * silu(z)) + RMSNorm + norm_w, bf16 out ----------------
__global__ __launch_bounds__(256) void gate_kernel(
    const __hip_bfloat16* __restrict__ yf, const __hip_bfloat16* __restrict__ yr,
    const __hip_bfloat16* __restrict__ z, const float* __restrict__ norm_w,
    __hip_bfloat16* __restrict__ yn)
{
    const int row = blockIdx.x, tid = threadIdx.x;
    const size_t ybase = (size_t)row * D_INNER;
    float yg[6]; float ss = 0.f;
    #pragma unroll
    for (int k = 0; k < 6; ++k) {
        int j = tid + k*256;
        float yv = __bfloat162float(yf[ybase+j]) + __bfloat162float(yr[ybase+j]);
        float zz = __bfloat162float(z[ybase+j]);
        float g  = yv * (zz / (1.f + __expf(-zz)));
        yg[k] = g; ss += g*g;
    }
    #pragma unroll
    for (int off = 32; off > 0; off >>= 1) ss += __shfl_down(ss, off, 64);
    __shared__ float red[4];
    if ((tid & 63) == 0) red[tid >> 6] = ss;
    __syncthreads();
    float total = red[0] + red[1] + red[2] + red[3];
    float rn = rsqrtf(total * (1.f/1536.f) + 1e-5f);
    #pragma unroll
    for (int k = 0; k < 6; ++k) {
        int j = tid + k*256;
        yn[ybase+j] = __float2bfloat16(yg[k] * rn * norm_w[j]);
    }
}

// ---------------- launch ----------------
extern "C" void kernel_launch(void* const* d_in, const int* in_sizes, int n_in,
                              void* d_out, int out_size, void* d_ws, size_t ws_size,
                              hipStream_t stream) {
    const float* u      = (const float*)d_in[0];
    const float* w_in   = (const float*)d_in[1];
    const float* conv_w = (const float*)d_in[2];
    const float* conv_b = (const float*)d_in[3];
    const float* norm_w = (const float*)d_in[4];
    const float* w_out  = (const float*)d_in[5];
    (void)in_sizes; (void)n_in; (void)out_size;

    char* ws = (char*)d_ws;
    const size_t nWin  = (size_t)D_IN_PROJ * D_MODEL;
    const size_t nWout = (size_t)D_MODEL * D_INNER;
    __hip_bfloat16* win_bf  = (__hip_bfloat16*)ws;
    __hip_bfloat16* wout_bf = (__hip_bfloat16*)(ws + nWin*2);
    float* wT = (float*)(ws + nWin*2 + nWout*2);
    const size_t wbytes = nWin*2 + nWout*2 + (size_t)9*CONV_DIM*4;
    char* arena = ws + wbytes;

    const size_t perRow = 10624;
    int CB = 32;
    while (CB > 1 && wbytes + perRow*(size_t)CB*1024 > ws_size) CB >>= 1;
    const int nchunks = 32 / CB;
    const size_t R = (size_t)CB * 1024;

    __hip_bfloat16* segA = (__hip_bfloat16*)arena;                 // u_bf, then yf
    char* pC = arena + R*3072;
    char* pD = pC + R*3584;
    char* pE = pD + R*384;
    __hip_bfloat16* xbc_bf  = (__hip_bfloat16*)pC;                 // then yr
    __hip_bfloat16* yr_bf   = (__hip_bfloat16*)pC;
    float*          dt_f32  = (float*)pD;
    __hip_bfloat16* conv_bf = (__hip_bfloat16*)pE;                 // then yn
    __hip_bfloat16* yn_bf   = (__hip_bfloat16*)pE;
    __hip_bfloat16* u_bf    = segA;
    __hip_bfloat16* yf_bf   = segA;

    cvt_kernel<<<(int)((nWin/4 + 255)/256), 256, 0, stream>>>(w_in, win_bf, (int)(nWin/4));
    cvt_kernel<<<(int)((nWout/4 + 255)/256), 256, 0, stream>>>(w_out, wout_bf, (int)(nWout/4));
    repack_w<<<(CONV_DIM*9 + 255)/256, 256, 0, stream>>>(conv_w, wT);

    for (int c = 0; c < nchunks; ++c) {
        const float* u_c = u + (size_t)c * R * D_MODEL;
        __hip_bfloat16* z_bf = (__hip_bfloat16*)((char*)d_out + (size_t)c * R * 3072);
        float* out_c = (float*)d_out + (size_t)c * R * D_MODEL;

        const size_t nUc4 = R * D_MODEL / 4;
        cvt_kernel<<<(int)((nUc4 + 255)/256), 256, 0, stream>>>(u_c, u_bf, (int)nUc4);

        gemm_bt<1><<<dim3((int)(R/128), (D_IN_PROJ + 127)/128), 256, 0, stream>>>(
            u_bf, win_bf, nullptr, z_bf, xbc_bf, dt_f32, (int)R, D_IN_PROJ, D_MODEL);

        conv_kernel<<<(int)((R*(CONV_DIM/8))/256), 256, 0, stream>>>(xbc_bf, wT, conv_b, conv_bf);

        scan_ssd<<<dim3(CB, NH, 2), 256, 0, stream>>>(
            (const __bf16*)conv_bf, dt_f32, (__bf16*)yf_bf, (__bf16*)yr_bf);

        gate_kernel<<<(int)R, 256, 0, stream>>>(yf_bf, yr_bf, z_bf, norm_w, yn_bf);

        gemm_bt<0><<<dim3((int)(R/128), D_MODEL/128), 256, 0, stream>>>(
            yn_bf, wout_bf, out_c, nullptr, nullptr, nullptr, (int)R, D_MODEL, D_INNER);
    }
}

// Round 4
// 1190.591 us; speedup vs baseline: 1.5348x; 1.1204x over previous
//
#include <hip/hip_runtime.h>
#include <hip/hip_bf16.h>
#include <stdint.h>

// ChimeraBlock (Mamba2-style) for MI355X.
// Round 8 (= round 7 resubmit, hardened barrier):
//   - bar_lds: s_waitcnt lgkmcnt(0) -> s_barrier -> sched_barrier(0). The
//     trailing sched_barrier pins post-barrier LDS reads behind the barrier
//     (llvm s_barrier is not a compiler memory fence; rule #18 analog).
//   - all barriers lgkmcnt-only: global prefetch/stores stay in flight
//   - full-chunk register prefetch (X/B/C/dt for chunk c+1 issued during c)
//   - B staged once in LDS (XOR-swizzled [s][n]); 5 barriers/chunk
//   - LDS 47.1KB -> 3 blocks/CU, launch_bounds(256,3)

#define D_MODEL 768
#define D_INNER 1536
#define NH 24
#define D_IN_PROJ 3424      // 2*1536 + 256 + 96
#define CONV_DIM 1792       // 1536 + 256
#define NDT 96
#define LSEQ 1024

typedef __bf16 bf16x8 __attribute__((ext_vector_type(8)));
typedef float f32x4 __attribute__((ext_vector_type(4)));

// ---------------- f32 -> bf16 convert (x4 vectorized) ----------------
__global__ void cvt_kernel(const float* __restrict__ src, __hip_bfloat16* __restrict__ dst, int n4) {
    int i = blockIdx.x * 256 + threadIdx.x;
    if (i < n4) {
        float4 v = ((const float4*)src)[i];
        __hip_bfloat162 lo, hi;
        lo.x = __float2bfloat16(v.x); lo.y = __float2bfloat16(v.y);
        hi.x = __float2bfloat16(v.z); hi.y = __float2bfloat16(v.w);
        ((__hip_bfloat162*)dst)[2*i]   = lo;
        ((__hip_bfloat162*)dst)[2*i+1] = hi;
    }
}

// ---------------- conv weight repack: (1792, 9) -> (9, 1792) ----------------
__global__ void repack_w(const float* __restrict__ cw, float* __restrict__ wT) {
    int i = blockIdx.x * 256 + threadIdx.x;
    if (i < CONV_DIM * 9) {
        int c = i / 9, t = i % 9;
        wT[t * CONV_DIM + c] = cw[i];
    }
}

// ---------------- bf16 NT GEMM: C[m,n] = sum_k A[m,k] * Bt[n,k] ----------------
__device__ __forceinline__ void gl_lds16(const __hip_bfloat16* g, __hip_bfloat16* l) {
    __builtin_amdgcn_global_load_lds(
        (const __attribute__((address_space(1))) void*)g,
        (__attribute__((address_space(3))) void*)l, 16, 0, 0);
}

// MODE 0: f32 out (OutF, width N).  MODE 1: split out -> Z(1536) | XBC(1792) | DT(96 f32)
template<int MODE>
__global__ __launch_bounds__(256) void gemm_bt(
    const __hip_bfloat16* __restrict__ A,   // M x K
    const __hip_bfloat16* __restrict__ Bt,  // N x K
    float* __restrict__ OutF,
    __hip_bfloat16* __restrict__ Z, __hip_bfloat16* __restrict__ XBC, float* __restrict__ DT,
    int M, int N, int K)
{
    __shared__ __hip_bfloat16 As[128*32];
    __shared__ __hip_bfloat16 Bs[128*32];
    const int tid  = threadIdx.x;
    const int wave = tid >> 6, lane = tid & 63;
    const int bm = blockIdx.x * 128, bn = blockIdx.y * 128;
    const int wm = (wave >> 1) * 64, wn = (wave & 1) * 64;
    f32x4 acc[4][4] = {};
    const int lrow = lane >> 2;
    const int lcol = (lane & 3) * 8;
    const int fr = lane & 15, fk = (lane >> 4) * 8;
    const int ktiles = K >> 5;
    for (int kt = 0; kt < ktiles; ++kt) {
        const int kofs = kt * 32;
        #pragma unroll
        for (int cc = 0; cc < 2; ++cc) {
            int r = (wave*2 + cc)*16 + lrow;
            gl_lds16(A + (size_t)(bm + r)*K + kofs + lcol, &As[r*32 + lcol]);
            int gn = bn + r; if (gn > N-1) gn = N-1;
            gl_lds16(Bt + (size_t)gn*K + kofs + lcol, &Bs[r*32 + lcol]);
        }
        __syncthreads();
        bf16x8 af[4], bfr[4];
        #pragma unroll
        for (int i = 0; i < 4; ++i)
            af[i] = *reinterpret_cast<const bf16x8*>(&As[(wm + i*16 + fr)*32 + fk]);
        #pragma unroll
        for (int j = 0; j < 4; ++j)
            bfr[j] = *reinterpret_cast<const bf16x8*>(&Bs[(wn + j*16 + fr)*32 + fk]);
        #pragma unroll
        for (int i = 0; i < 4; ++i)
            #pragma unroll
            for (int j = 0; j < 4; ++j)
                acc[i][j] = __builtin_amdgcn_mfma_f32_16x16x32_bf16(af[i], bfr[j], acc[i][j], 0, 0, 0);
        __syncthreads();
    }
    const int er = (lane >> 4) * 4;
    const int ec = lane & 15;
    #pragma unroll
    for (int i = 0; i < 4; ++i) {
        #pragma unroll
        for (int j = 0; j < 4; ++j) {
            #pragma unroll
            for (int r = 0; r < 4; ++r) {
                int row = bm + wm + i*16 + er + r;
                int col = bn + wn + j*16 + ec;
                if (col < N) {
                    float v = acc[i][j][r];
                    if (MODE == 0) {
                        OutF[(size_t)row*N + col] = v;
                    } else {
                        if (col < D_INNER)
                            Z[(size_t)row*D_INNER + col] = __float2bfloat16(v);
                        else if (col < 3328)
                            XBC[(size_t)row*CONV_DIM + (col - D_INNER)] = __float2bfloat16(v);
                        else
                            DT[(size_t)row*NDT + (col - 3328)] = v;
                    }
                }
            }
        }
    }
}

// ---------------- depthwise 3x3 conv + bias + SiLU, 8 ch/thread ----------------
__global__ __launch_bounds__(256) void conv_kernel(
    const __hip_bfloat16* __restrict__ xbc, // (R, 1792)
    const float* __restrict__ wT,           // (9, 1792) repacked
    const float* __restrict__ cb,           // (1792)
    __hip_bfloat16* __restrict__ out)       // (R, 1792)
{
    size_t idx = (size_t)blockIdx.x * 256 + threadIdx.x;   // R * 224 threads
    const int cg = (int)(idx % (CONV_DIM / 8));
    const int c = cg * 8;
    size_t bp = idx / (CONV_DIM / 8);
    const int pix = (int)(bp % LSEQ);
    const int b = (int)(bp / LSEQ);
    const int y = pix >> 5, x = pix & 31;
    float acc[8];
    {
        float4 c0 = *(const float4*)(cb + c);
        float4 c1 = *(const float4*)(cb + c + 4);
        acc[0]=c0.x; acc[1]=c0.y; acc[2]=c0.z; acc[3]=c0.w;
        acc[4]=c1.x; acc[5]=c1.y; acc[6]=c1.z; acc[7]=c1.w;
    }
    const size_t rowbase = (size_t)b * LSEQ;
    #pragma unroll
    for (int dy = -1; dy <= 1; ++dy) {
        int yy = y + dy; if (yy < 0 || yy > 31) continue;
        #pragma unroll
        for (int dx = -1; dx <= 1; ++dx) {
            int xx = x + dx; if (xx < 0 || xx > 31) continue;
            const int t = (dy+1)*3 + (dx+1);
            bf16x8 v = *(const bf16x8*)(xbc + (rowbase + yy*32 + xx)*(size_t)CONV_DIM + c);
            float4 w0 = *(const float4*)(wT + t*CONV_DIM + c);
            float4 w1 = *(const float4*)(wT + t*CONV_DIM + c + 4);
            acc[0] += w0.x * (float)v[0];
            acc[1] += w0.y * (float)v[1];
            acc[2] += w0.z * (float)v[2];
            acc[3] += w0.w * (float)v[3];
            acc[4] += w1.x * (float)v[4];
            acc[5] += w1.y * (float)v[5];
            acc[6] += w1.z * (float)v[6];
            acc[7] += w1.w * (float)v[7];
        }
    }
    bf16x8 o;
    #pragma unroll
    for (int i = 0; i < 8; ++i) {
        float s = acc[i] / (1.f + __expf(-acc[i]));
        o[i] = (__bf16)s;
    }
    *(bf16x8*)(out + (rowbase + pix)*(size_t)CONV_DIM + c) = o;
}

// ---------------- chunked SSD scan on MFMA ----------------
#define PADW 72
__device__ __forceinline__ f32x4 mfma16(bf16x8 a, bf16x8 b, f32x4 c) {
    return __builtin_amdgcn_mfma_f32_16x16x32_bf16(a, b, c, 0, 0, 0);
}
// LDS-only barrier: waits own LDS ops (lgkmcnt), does NOT drain vmcnt, and
// pins post-barrier code behind the barrier (sched_barrier) so consumer
// ds_reads cannot hoist between waitcnt and s_barrier.
__device__ __forceinline__ void bar_lds() {
    asm volatile("s_waitcnt lgkmcnt(0)" ::: "memory");
    __builtin_amdgcn_s_barrier();
    __builtin_amdgcn_sched_barrier(0);
}

__global__ __launch_bounds__(256, 3) void scan_ssd(
    const __bf16* __restrict__ conv,   // (R, 1792): x | B(2x64) | C(2x64)
    const float* __restrict__ dtraw,   // (R, 96): [k][h], k = 2g + dir
    __bf16* __restrict__ yf,           // (R, 1536)
    __bf16* __restrict__ yr)           // (R, 1536)
{
    const int tid = threadIdx.x;
    const int w = tid >> 6, lane = tid & 63;
    const int b = blockIdx.x, h = blockIdx.y, dir = blockIdx.z;
    __bf16* yout = dir ? yr : yf;
    const size_t base = (size_t)b * LSEQ;

    __shared__ __align__(16) __bf16 XT[64*PADW];  // X^T: [p][tau ^ swz(p)]
    __shared__ __align__(16) __bf16 Gs[64*PADW];  // G': [tau][s]; reused as y-stage [tau][p]
    __shared__ __align__(16) __bf16 Ts[64*PADW];  // (wB)^T: [n][s ^ swz(n)]
    __shared__ __align__(16) __bf16 HT[64*PADW];  // H^T: [p][n]
    __shared__ __align__(16) __bf16 Bss[64*64];   // B: [s][n ^ ((s&7)<<3)]
    __shared__ float Sarr[2][64], Dtar[2][64], Warr[2][64], Earr[2][64];

    f32x4 Hst0[4] = {}, Hst1[4] = {};      // state H[n][p] per group: n-slab = wave

    const int srow = tid >> 2;             // staging: physical row offset 0..63
    const int scol = (tid & 3) * 16;       // staging: 16-element column group
    const int fr = lane & 15, fkq = (lane >> 4) * 8;   // frag row / k base
    const int er = (lane >> 4) * 4, ec = lane & 15;    // C/D row base / col
    const int rn = w*16 + fr;
    const int sl = dir ? 63 - srow : srow; // logical scan index of staged row

    // ---- per-chunk-stepped global pointers ----
    const int rA0 = dir ? (LSEQ - 64) : 0;
    const ptrdiff_t dRow = (ptrdiff_t)(dir ? -64 : 64) * CONV_DIM;
    const ptrdiff_t dDt  = (ptrdiff_t)(dir ? -64 : 64) * NDT;
    const __bf16* pRow = conv + (base + rA0 + srow) * (size_t)CONV_DIM;       // staging row
    const __bf16* pC   = conv + (base + rA0 + (dir ? 63 - rn : rn)) * (size_t)CONV_DIM + 1664;
    const float*  pDt  = dtraw + (base + rA0 + (dir ? 63 - lane : lane)) * NDT
                         + (2*(tid >> 6) + dir)*24 + h;                       // valid for tid<128
    const int xoff = h*64 + scol;

    // ---- prefetch chunk 0 ----
    bf16x8 pfx0 = *(const bf16x8*)(pRow + xoff);
    bf16x8 pfx1 = *(const bf16x8*)(pRow + xoff + 8);
    bf16x8 pfbA0 = *(const bf16x8*)(pRow + 1536 + scol);
    bf16x8 pfbA1 = *(const bf16x8*)(pRow + 1536 + scol + 8);
    bf16x8 pfbB0 = *(const bf16x8*)(pRow + 1600 + scol);
    bf16x8 pfbB1 = *(const bf16x8*)(pRow + 1600 + scol + 8);
    bf16x8 pfc00 = *(const bf16x8*)(pC + fkq);
    bf16x8 pfc01 = *(const bf16x8*)(pC + 32 + fkq);
    bf16x8 pfc10 = *(const bf16x8*)(pC + 64 + fkq);
    bf16x8 pfc11 = *(const bf16x8*)(pC + 96 + fkq);
    float pfd = 0.f;
    if (tid < 128) pfd = *pDt;

    #pragma unroll 1
    for (int c = 0; c < 16; ++c) {
        const int rA = dir ? (LSEQ - (c+1)*64) : c*64;   // physical start row

        // copy prefetched values consumed later this chunk (pf regs get reissued)
        bf16x8 bA0 = pfbA0, bA1 = pfbA1, bB0 = pfbB0, bB1 = pfbB1;
        bf16x8 c00 = pfc00, c01 = pfc01, c10 = pfc10, c11 = pfc11;

        {   // stage X^T (swizzled scatter-transpose) from prefetch regs
            const int tau = sl;
            #pragma unroll
            for (int i = 0; i < 8; ++i) {
                const int p = scol + i;
                XT[p*PADW + (tau ^ (((p >> 3) & 7) << 3))] = pfx0[i];
            }
            #pragma unroll
            for (int i = 0; i < 8; ++i) {
                const int p = scol + 8 + i;
                XT[p*PADW + (tau ^ (((p >> 3) & 7) << 3))] = pfx1[i];
            }
            if (tid < 128) {   // S arrays from prefetched dt
                const int g = tid >> 6;
                const int t2 = lane;
                float e = __expf(pfd);
                float dts = __logf(1.f + e);               // softplus
                float s = dts;
                #pragma unroll
                for (int off = 1; off < 64; off <<= 1) {   // inclusive prefix sum
                    float v = __shfl_up(s, off, 64);
                    if (lane >= off) s += v;
                }
                float stot = __shfl(s, 63, 64);
                Sarr[g][t2] = s;
                Dtar[g][t2] = dts;
                Warr[g][t2] = __expf(s - stot) * dts;
                Earr[g][t2] = __expf(-s);
            }
        }
        // issue prefetch for chunk c+1 (stays in flight across all barriers)
        if (c != 15) {
            pRow += dRow; pC += dRow; pDt += dDt;
            pfx0 = *(const bf16x8*)(pRow + xoff);
            pfx1 = *(const bf16x8*)(pRow + xoff + 8);
            pfbA0 = *(const bf16x8*)(pRow + 1536 + scol);
            pfbA1 = *(const bf16x8*)(pRow + 1536 + scol + 8);
            pfbB0 = *(const bf16x8*)(pRow + 1600 + scol);
            pfbB1 = *(const bf16x8*)(pRow + 1600 + scol + 8);
            pfc00 = *(const bf16x8*)(pC + fkq);
            pfc01 = *(const bf16x8*)(pC + 32 + fkq);
            pfc10 = *(const bf16x8*)(pC + 64 + fkq);
            pfc11 = *(const bf16x8*)(pC + 96 + fkq);
            if (tid < 128) pfd = *pDt;
        }
        bar_lds();   // (a) XT/S ready

        f32x4 Yacc[4] = {};

        auto group = [&](const int g, f32x4 (&Hst)[4],
                         bf16x8 bR0, bf16x8 bR1, bf16x8 cf0, bf16x8 cf1) {
            {   // stage Ts (scattered, w-scaled) + Bss (vector, swizzled) from B-row regs
                const float ws = Warr[g][sl];
                const int rsw = (sl & 7) << 3;
                #pragma unroll
                for (int i = 0; i < 8; ++i) {
                    const int n = scol + i;
                    Ts[n*PADW + (sl ^ (((n >> 3) & 7) << 3))] = (__bf16)((float)bR0[i] * ws);
                }
                #pragma unroll
                for (int i = 0; i < 8; ++i) {
                    const int n = scol + 8 + i;
                    Ts[n*PADW + (sl ^ (((n >> 3) & 7) << 3))] = (__bf16)((float)bR1[i] * ws);
                }
                *(bf16x8*)&Bss[sl*64 + (scol ^ rsw)] = bR0;
                *(bf16x8*)&Bss[sl*64 + ((scol + 8) ^ rsw)] = bR1;
            }
            // write H^T (h_init, unscaled) from regs, packed bf16x2
            #pragma unroll
            for (int t4 = 0; t4 < 4; ++t4) {
                const int p = t4*16 + ec;
                #pragma unroll
                for (int j = 0; j < 2; ++j) {
                    const int n = w*16 + er + 2*j;
                    __hip_bfloat162 pr;
                    pr.x = __float2bfloat16(Hst[t4][2*j]);
                    pr.y = __float2bfloat16(Hst[t4][2*j+1]);
                    *(__hip_bfloat162*)&HT[p*PADW + n] = pr;
                }
            }
            bar_lds();   // (c) Ts/Bss/HT ready
            // G = C B^T (K = n = 64), B frags from LDS
            f32x4 Gacc[4] = {};
            #pragma unroll
            for (int s4 = 0; s4 < 4; ++s4) {
                const int s = s4*16 + fr;
                const int ssw = (s & 7) << 3;
                bf16x8 bb0 = *(const bf16x8*)&Bss[s*64 + (fkq ^ ssw)];
                bf16x8 bb1 = *(const bf16x8*)&Bss[s*64 + ((32 + fkq) ^ ssw)];
                Gacc[s4] = mfma16(cf0, bb0, Gacc[s4]);
                Gacc[s4] = mfma16(cf1, bb1, Gacc[s4]);
            }
            // scale H regs by chunk decay
            const float e63 = Earr[g][63];
            #pragma unroll
            for (int t4 = 0; t4 < 4; ++t4)
                #pragma unroll
                for (int rr = 0; rr < 4; ++rr) Hst[t4][rr] *= e63;
            // mask G -> Gs (wave-private rows; no barrier needed before own reads)
            #pragma unroll
            for (int s4 = 0; s4 < 4; ++s4) {
                const int s = s4*16 + ec;
                const float Ss = Sarr[g][s], dts = Dtar[g][s];
                #pragma unroll
                for (int rr = 0; rr < 4; ++rr) {
                    const int tau = w*16 + er + rr;
                    float m = (tau >= s) ? __expf(Ss - Sarr[g][tau]) * dts : 0.f;
                    Gs[tau*PADW + s] = (__bf16)(Gacc[s4][rr] * m);
                }
            }
            // Y += G' X + (E*C) H ; H += (wB)^T X
            bf16x8 ga0 = *(const bf16x8*)&Gs[rn*PADW + fkq];
            bf16x8 ga1 = *(const bf16x8*)&Gs[rn*PADW + 32 + fkq];
            const float esc = Earr[g][rn];
            bf16x8 ca0, ca1;
            #pragma unroll
            for (int i = 0; i < 8; ++i) {
                ca0[i] = (__bf16)((float)cf0[i] * esc);
                ca1[i] = (__bf16)((float)cf1[i] * esc);
            }
            const int Sn = ((rn >> 3) & 7) << 3;
            bf16x8 ta0 = *(const bf16x8*)&Ts[rn*PADW + (fkq ^ Sn)];
            bf16x8 ta1 = *(const bf16x8*)&Ts[rn*PADW + ((32 + fkq) ^ Sn)];
            #pragma unroll
            for (int p4 = 0; p4 < 4; ++p4) {
                const int p = p4*16 + fr;
                const int Sp = ((p >> 3) & 7) << 3;
                bf16x8 x0 = *(const bf16x8*)&XT[p*PADW + (fkq ^ Sp)];
                bf16x8 x1 = *(const bf16x8*)&XT[p*PADW + ((32 + fkq) ^ Sp)];
                bf16x8 h0 = *(const bf16x8*)&HT[p*PADW + fkq];
                bf16x8 h1 = *(const bf16x8*)&HT[p*PADW + 32 + fkq];
                Yacc[p4] = mfma16(ga0, x0, Yacc[p4]);
                Yacc[p4] = mfma16(ga1, x1, Yacc[p4]);
                Yacc[p4] = mfma16(ca0, h0, Yacc[p4]);
                Yacc[p4] = mfma16(ca1, h1, Yacc[p4]);
                Hst[p4] = mfma16(ta0, x0, Hst[p4]);
                Hst[p4] = mfma16(ta1, x1, Hst[p4]);
            }
        };

        group(0, Hst0, bA0, bA1, c00, c01);
        bar_lds();   // WAR: g1's Ts/Bss/HT writes vs g0's reads
        group(1, Hst1, bB0, bB1, c10, c11);

        // y-stage into Gs (wave-private rows; own ga reads already retired in order)
        #pragma unroll
        for (int p4 = 0; p4 < 4; ++p4)
            #pragma unroll
            for (int rr = 0; rr < 4; ++rr) {
                const int tau = w*16 + er + rr;
                Gs[tau*PADW + p4*16 + ec] = (__bf16)Yacc[p4][rr];
            }
        bar_lds();   // (y)
        {   // coalesced y store: 2 x 16B per thread (store stays in flight)
            const int rowp = rA + (dir ? 63 - srow : srow);
            bf16x8 y0 = *(const bf16x8*)&Gs[srow*PADW + scol];
            bf16x8 y1 = *(const bf16x8*)&Gs[srow*PADW + scol + 8];
            __bf16* dst = yout + (base + rowp)*(size_t)D_INNER + h*64 + scol;
            *(bf16x8*)dst = y0;
            *(bf16x8*)(dst + 8) = y1;
        }
    }
}

// ---------------- gate (y * silu(z)) + RMSNorm + norm_w, bf16 out ----------------
__global__ __launch_bounds__(256) void gate_kernel(
    const __hip_bfloat16* __restrict__ yf, const __hip_bfloat16* __restrict__ yr,
    const __hip_bfloat16* __restrict__ z, const float* __restrict__ norm_w,
    __hip_bfloat16* __restrict__ yn)
{
    const int row = blockIdx.x, tid = threadIdx.x;
    const size_t ybase = (size_t)row * D_INNER;
    float yg[6]; float ss = 0.f;
    #pragma unroll
    for (int k = 0; k < 6; ++k) {
        int j = tid + k*256;
        float yv = __bfloat162float(yf[ybase+j]) + __bfloat162float(yr[ybase+j]);
        float zz = __bfloat162float(z[ybase+j]);
        float g  = yv * (zz / (1.f + __expf(-zz)));
        yg[k] = g; ss += g*g;
    }
    #pragma unroll
    for (int off = 32; off > 0; off >>= 1) ss += __shfl_down(ss, off, 64);
    __shared__ float red[4];
    if ((tid & 63) == 0) red[tid >> 6] = ss;
    __syncthreads();
    float total = red[0] + red[1] + red[2] + red[3];
    float rn = rsqrtf(total * (1.f/1536.f) + 1e-5f);
    #pragma unroll
    for (int k = 0; k < 6; ++k) {
        int j = tid + k*256;
        yn[ybase+j] = __float2bfloat16(yg[k] * rn * norm_w[j]);
    }
}

// ---------------- launch ----------------
extern "C" void kernel_launch(void* const* d_in, const int* in_sizes, int n_in,
                              void* d_out, int out_size, void* d_ws, size_t ws_size,
                              hipStream_t stream) {
    const float* u      = (const float*)d_in[0];
    const float* w_in   = (const float*)d_in[1];
    const float* conv_w = (const float*)d_in[2];
    const float* conv_b = (const float*)d_in[3];
    const float* norm_w = (const float*)d_in[4];
    const float* w_out  = (const float*)d_in[5];
    (void)in_sizes; (void)n_in; (void)out_size;

    char* ws = (char*)d_ws;
    const size_t nWin  = (size_t)D_IN_PROJ * D_MODEL;
    const size_t nWout = (size_t)D_MODEL * D_INNER;
    __hip_bfloat16* win_bf  = (__hip_bfloat16*)ws;
    __hip_bfloat16* wout_bf = (__hip_bfloat16*)(ws + nWin*2);
    float* wT = (float*)(ws + nWin*2 + nWout*2);
    const size_t wbytes = nWin*2 + nWout*2 + (size_t)9*CONV_DIM*4;
    char* arena = ws + wbytes;

    const size_t perRow = 10624;
    int CB = 32;
    while (CB > 1 && wbytes + perRow*(size_t)CB*1024 > ws_size) CB >>= 1;
    const int nchunks = 32 / CB;
    const size_t R = (size_t)CB * 1024;

    __hip_bfloat16* segA = (__hip_bfloat16*)arena;                 // u_bf, then yf
    char* pC = arena + R*3072;
    char* pD = pC + R*3584;
    char* pE = pD + R*384;
    __hip_bfloat16* xbc_bf  = (__hip_bfloat16*)pC;                 // then yr
    __hip_bfloat16* yr_bf   = (__hip_bfloat16*)pC;
    float*          dt_f32  = (float*)pD;
    __hip_bfloat16* conv_bf = (__hip_bfloat16*)pE;                 // then yn
    __hip_bfloat16* yn_bf   = (__hip_bfloat16*)pE;
    __hip_bfloat16* u_bf    = segA;
    __hip_bfloat16* yf_bf   = segA;

    cvt_kernel<<<(int)((nWin/4 + 255)/256), 256, 0, stream>>>(w_in, win_bf, (int)(nWin/4));
    cvt_kernel<<<(int)((nWout/4 + 255)/256), 256, 0, stream>>>(w_out, wout_bf, (int)(nWout/4));
    repack_w<<<(CONV_DIM*9 + 255)/256, 256, 0, stream>>>(conv_w, wT);

    for (int c = 0; c < nchunks; ++c) {
        const float* u_c = u + (size_t)c * R * D_MODEL;
        __hip_bfloat16* z_bf = (__hip_bfloat16*)((char*)d_out + (size_t)c * R * 3072);
        float* out_c = (float*)d_out + (size_t)c * R * D_MODEL;

        const size_t nUc4 = R * D_MODEL / 4;
        cvt_kernel<<<(int)((nUc4 + 255)/256), 256, 0, stream>>>(u_c, u_bf, (int)nUc4);

        gemm_bt<1><<<dim3((int)(R/128), (D_IN_PROJ + 127)/128), 256, 0, stream>>>(
            u_bf, win_bf, nullptr, z_bf, xbc_bf, dt_f32, (int)R, D_IN_PROJ, D_MODEL);

        conv_kernel<<<(int)((R*(CONV_DIM/8))/256), 256, 0, stream>>>(xbc_bf, wT, conv_b, conv_bf);

        scan_ssd<<<dim3(CB, NH, 2), 256, 0, stream>>>(
            (const __bf16*)conv_bf, dt_f32, (__bf16*)yf_bf, (__bf16*)yr_bf);

        gate_kernel<<<(int)R, 256, 0, stream>>>(yf_bf, yr_bf, z_bf, norm_w, yn_bf);

        gemm_bt<0><<<dim3((int)(R/128), D_MODEL/128), 256, 0, stream>>>(
            yn_bf, wout_bf, out_c, nullptr, nullptr, nullptr, (int)R, D_MODEL, D_INNER);
    }
}

// Round 5
// 1153.967 us; speedup vs baseline: 1.5836x; 1.0317x over previous
//
#include <hip/hip_runtime.h>
#include <hip/hip_bf16.h>
#include <stdint.h>

// ChimeraBlock (Mamba2-style) for MI355X.
// Round 9 (on top of round-8 structure):
//   - mask exp factored: m[tau,s] = Wm[s]*Rm[tau], precomputed per chunk by the
//     tid<128 prefix-sum crew (mid-centered, overflow-safe). Removes 32
//     __expf + ~24 LDS scalar reads per thread per chunk (VALU was 2.2x MFMA).
//   - y output layout [h][row][64]: each block streams full cache lines
//     (was 128B slivers of 3KB rows shared by 24 blocks -> 2.5x write amp).
//     gate_kernel reads the new layout coalesced.
//   - s_setprio(1) around MFMA clusters (T5; independent blocks = right regime).
//   - keeps: lgkmcnt-only barriers, full-chunk register prefetch, LDS-staged B,
//     5 barriers/chunk, 47KB LDS, 3 blocks/CU.

#define D_MODEL 768
#define D_INNER 1536
#define NH 24
#define D_IN_PROJ 3424      // 2*1536 + 256 + 96
#define CONV_DIM 1792       // 1536 + 256
#define NDT 96
#define LSEQ 1024

typedef __bf16 bf16x8 __attribute__((ext_vector_type(8)));
typedef float f32x4 __attribute__((ext_vector_type(4)));

// ---------------- f32 -> bf16 convert (x4 vectorized) ----------------
__global__ void cvt_kernel(const float* __restrict__ src, __hip_bfloat16* __restrict__ dst, int n4) {
    int i = blockIdx.x * 256 + threadIdx.x;
    if (i < n4) {
        float4 v = ((const float4*)src)[i];
        __hip_bfloat162 lo, hi;
        lo.x = __float2bfloat16(v.x); lo.y = __float2bfloat16(v.y);
        hi.x = __float2bfloat16(v.z); hi.y = __float2bfloat16(v.w);
        ((__hip_bfloat162*)dst)[2*i]   = lo;
        ((__hip_bfloat162*)dst)[2*i+1] = hi;
    }
}

// ---------------- conv weight repack: (1792, 9) -> (9, 1792) ----------------
__global__ void repack_w(const float* __restrict__ cw, float* __restrict__ wT) {
    int i = blockIdx.x * 256 + threadIdx.x;
    if (i < CONV_DIM * 9) {
        int c = i / 9, t = i % 9;
        wT[t * CONV_DIM + c] = cw[i];
    }
}

// ---------------- bf16 NT GEMM: C[m,n] = sum_k A[m,k] * Bt[n,k] ----------------
__device__ __forceinline__ void gl_lds16(const __hip_bfloat16* g, __hip_bfloat16* l) {
    __builtin_amdgcn_global_load_lds(
        (const __attribute__((address_space(1))) void*)g,
        (__attribute__((address_space(3))) void*)l, 16, 0, 0);
}

// MODE 0: f32 out (OutF, width N).  MODE 1: split out -> Z(1536) | XBC(1792) | DT(96 f32)
template<int MODE>
__global__ __launch_bounds__(256) void gemm_bt(
    const __hip_bfloat16* __restrict__ A,   // M x K
    const __hip_bfloat16* __restrict__ Bt,  // N x K
    float* __restrict__ OutF,
    __hip_bfloat16* __restrict__ Z, __hip_bfloat16* __restrict__ XBC, float* __restrict__ DT,
    int M, int N, int K)
{
    __shared__ __hip_bfloat16 As[128*32];
    __shared__ __hip_bfloat16 Bs[128*32];
    const int tid  = threadIdx.x;
    const int wave = tid >> 6, lane = tid & 63;
    const int bm = blockIdx.x * 128, bn = blockIdx.y * 128;
    const int wm = (wave >> 1) * 64, wn = (wave & 1) * 64;
    f32x4 acc[4][4] = {};
    const int lrow = lane >> 2;
    const int lcol = (lane & 3) * 8;
    const int fr = lane & 15, fk = (lane >> 4) * 8;
    const int ktiles = K >> 5;
    for (int kt = 0; kt < ktiles; ++kt) {
        const int kofs = kt * 32;
        #pragma unroll
        for (int cc = 0; cc < 2; ++cc) {
            int r = (wave*2 + cc)*16 + lrow;
            gl_lds16(A + (size_t)(bm + r)*K + kofs + lcol, &As[r*32 + lcol]);
            int gn = bn + r; if (gn > N-1) gn = N-1;
            gl_lds16(Bt + (size_t)gn*K + kofs + lcol, &Bs[r*32 + lcol]);
        }
        __syncthreads();
        bf16x8 af[4], bfr[4];
        #pragma unroll
        for (int i = 0; i < 4; ++i)
            af[i] = *reinterpret_cast<const bf16x8*>(&As[(wm + i*16 + fr)*32 + fk]);
        #pragma unroll
        for (int j = 0; j < 4; ++j)
            bfr[j] = *reinterpret_cast<const bf16x8*>(&Bs[(wn + j*16 + fr)*32 + fk]);
        #pragma unroll
        for (int i = 0; i < 4; ++i)
            #pragma unroll
            for (int j = 0; j < 4; ++j)
                acc[i][j] = __builtin_amdgcn_mfma_f32_16x16x32_bf16(af[i], bfr[j], acc[i][j], 0, 0, 0);
        __syncthreads();
    }
    const int er = (lane >> 4) * 4;
    const int ec = lane & 15;
    #pragma unroll
    for (int i = 0; i < 4; ++i) {
        #pragma unroll
        for (int j = 0; j < 4; ++j) {
            #pragma unroll
            for (int r = 0; r < 4; ++r) {
                int row = bm + wm + i*16 + er + r;
                int col = bn + wn + j*16 + ec;
                if (col < N) {
                    float v = acc[i][j][r];
                    if (MODE == 0) {
                        OutF[(size_t)row*N + col] = v;
                    } else {
                        if (col < D_INNER)
                            Z[(size_t)row*D_INNER + col] = __float2bfloat16(v);
                        else if (col < 3328)
                            XBC[(size_t)row*CONV_DIM + (col - D_INNER)] = __float2bfloat16(v);
                        else
                            DT[(size_t)row*NDT + (col - 3328)] = v;
                    }
                }
            }
        }
    }
}

// ---------------- depthwise 3x3 conv + bias + SiLU, 8 ch/thread ----------------
__global__ __launch_bounds__(256) void conv_kernel(
    const __hip_bfloat16* __restrict__ xbc, // (R, 1792)
    const float* __restrict__ wT,           // (9, 1792) repacked
    const float* __restrict__ cb,           // (1792)
    __hip_bfloat16* __restrict__ out)       // (R, 1792)
{
    size_t idx = (size_t)blockIdx.x * 256 + threadIdx.x;   // R * 224 threads
    const int cg = (int)(idx % (CONV_DIM / 8));
    const int c = cg * 8;
    size_t bp = idx / (CONV_DIM / 8);
    const int pix = (int)(bp % LSEQ);
    const int b = (int)(bp / LSEQ);
    const int y = pix >> 5, x = pix & 31;
    float acc[8];
    {
        float4 c0 = *(const float4*)(cb + c);
        float4 c1 = *(const float4*)(cb + c + 4);
        acc[0]=c0.x; acc[1]=c0.y; acc[2]=c0.z; acc[3]=c0.w;
        acc[4]=c1.x; acc[5]=c1.y; acc[6]=c1.z; acc[7]=c1.w;
    }
    const size_t rowbase = (size_t)b * LSEQ;
    #pragma unroll
    for (int dy = -1; dy <= 1; ++dy) {
        int yy = y + dy; if (yy < 0 || yy > 31) continue;
        #pragma unroll
        for (int dx = -1; dx <= 1; ++dx) {
            int xx = x + dx; if (xx < 0 || xx > 31) continue;
            const int t = (dy+1)*3 + (dx+1);
            bf16x8 v = *(const bf16x8*)(xbc + (rowbase + yy*32 + xx)*(size_t)CONV_DIM + c);
            float4 w0 = *(const float4*)(wT + t*CONV_DIM + c);
            float4 w1 = *(const float4*)(wT + t*CONV_DIM + c + 4);
            acc[0] += w0.x * (float)v[0];
            acc[1] += w0.y * (float)v[1];
            acc[2] += w0.z * (float)v[2];
            acc[3] += w0.w * (float)v[3];
            acc[4] += w1.x * (float)v[4];
            acc[5] += w1.y * (float)v[5];
            acc[6] += w1.z * (float)v[6];
            acc[7] += w1.w * (float)v[7];
        }
    }
    bf16x8 o;
    #pragma unroll
    for (int i = 0; i < 8; ++i) {
        float s = acc[i] / (1.f + __expf(-acc[i]));
        o[i] = (__bf16)s;
    }
    *(bf16x8*)(out + (rowbase + pix)*(size_t)CONV_DIM + c) = o;
}

// ---------------- chunked SSD scan on MFMA ----------------
#define PADW 72
__device__ __forceinline__ f32x4 mfma16(bf16x8 a, bf16x8 b, f32x4 c) {
    return __builtin_amdgcn_mfma_f32_16x16x32_bf16(a, b, c, 0, 0, 0);
}
// LDS-only barrier: waits own LDS ops (lgkmcnt), does NOT drain vmcnt, and
// pins post-barrier code behind the barrier (sched_barrier).
__device__ __forceinline__ void bar_lds() {
    asm volatile("s_waitcnt lgkmcnt(0)" ::: "memory");
    __builtin_amdgcn_s_barrier();
    __builtin_amdgcn_sched_barrier(0);
}

__global__ __launch_bounds__(256, 3) void scan_ssd(
    const __bf16* __restrict__ conv,   // (R, 1792): x | B(2x64) | C(2x64)
    const float* __restrict__ dtraw,   // (R, 96): [k][h], k = 2g + dir
    __bf16* __restrict__ yf,           // (NH, R, 64)
    __bf16* __restrict__ yr)           // (NH, R, 64)
{
    const int tid = threadIdx.x;
    const int w = tid >> 6, lane = tid & 63;
    const int b = blockIdx.x, h = blockIdx.y, dir = blockIdx.z;
    __bf16* yout = dir ? yr : yf;
    const size_t base = (size_t)b * LSEQ;
    const size_t Rtot = (size_t)gridDim.x * LSEQ;

    __shared__ __align__(16) __bf16 XT[64*PADW];  // X^T: [p][tau ^ swz(p)]
    __shared__ __align__(16) __bf16 Gs[64*PADW];  // G': [tau][s]; reused as y-stage [tau][p]
    __shared__ __align__(16) __bf16 Ts[64*PADW];  // (wB)^T: [n][s ^ swz(n)]
    __shared__ __align__(16) __bf16 HT[64*PADW];  // H^T: [p][n]
    __shared__ __align__(16) __bf16 Bss[64*64];   // B: [s][n ^ ((s&7)<<3)]
    __shared__ float Warr[2][64], Earr[2][64], Wmarr[2][64], Rmarr[2][64];

    f32x4 Hst0[4] = {}, Hst1[4] = {};      // state H[n][p] per group: n-slab = wave

    const int srow = tid >> 2;             // staging: physical row offset 0..63
    const int scol = (tid & 3) * 16;       // staging: 16-element column group
    const int fr = lane & 15, fkq = (lane >> 4) * 8;   // frag row / k base
    const int er = (lane >> 4) * 4, ec = lane & 15;    // C/D row base / col
    const int rn = w*16 + fr;
    const int sl = dir ? 63 - srow : srow; // logical scan index of staged row

    // ---- per-chunk-stepped global pointers ----
    const int rA0 = dir ? (LSEQ - 64) : 0;
    const ptrdiff_t dRow = (ptrdiff_t)(dir ? -64 : 64) * CONV_DIM;
    const ptrdiff_t dDt  = (ptrdiff_t)(dir ? -64 : 64) * NDT;
    const __bf16* pRow = conv + (base + rA0 + srow) * (size_t)CONV_DIM;       // staging row
    const __bf16* pC   = conv + (base + rA0 + (dir ? 63 - rn : rn)) * (size_t)CONV_DIM + 1664;
    const float*  pDt  = dtraw + (base + rA0 + (dir ? 63 - lane : lane)) * NDT
                         + (2*(tid >> 6) + dir)*24 + h;                       // valid for tid<128
    const int xoff = h*64 + scol;

    // ---- prefetch chunk 0 ----
    bf16x8 pfx0 = *(const bf16x8*)(pRow + xoff);
    bf16x8 pfx1 = *(const bf16x8*)(pRow + xoff + 8);
    bf16x8 pfbA0 = *(const bf16x8*)(pRow + 1536 + scol);
    bf16x8 pfbA1 = *(const bf16x8*)(pRow + 1536 + scol + 8);
    bf16x8 pfbB0 = *(const bf16x8*)(pRow + 1600 + scol);
    bf16x8 pfbB1 = *(const bf16x8*)(pRow + 1600 + scol + 8);
    bf16x8 pfc00 = *(const bf16x8*)(pC + fkq);
    bf16x8 pfc01 = *(const bf16x8*)(pC + 32 + fkq);
    bf16x8 pfc10 = *(const bf16x8*)(pC + 64 + fkq);
    bf16x8 pfc11 = *(const bf16x8*)(pC + 96 + fkq);
    float pfd = 0.f;
    if (tid < 128) pfd = *pDt;

    #pragma unroll 1
    for (int c = 0; c < 16; ++c) {
        const int rA = dir ? (LSEQ - (c+1)*64) : c*64;   // physical start row

        // copy prefetched values consumed later this chunk (pf regs get reissued)
        bf16x8 bA0 = pfbA0, bA1 = pfbA1, bB0 = pfbB0, bB1 = pfbB1;
        bf16x8 c00 = pfc00, c01 = pfc01, c10 = pfc10, c11 = pfc11;

        {   // stage X^T (swizzled scatter-transpose) from prefetch regs
            const int tau = sl;
            #pragma unroll
            for (int i = 0; i < 8; ++i) {
                const int p = scol + i;
                XT[p*PADW + (tau ^ (((p >> 3) & 7) << 3))] = pfx0[i];
            }
            #pragma unroll
            for (int i = 0; i < 8; ++i) {
                const int p = scol + 8 + i;
                XT[p*PADW + (tau ^ (((p >> 3) & 7) << 3))] = pfx1[i];
            }
            if (tid < 128) {   // per-chunk scan arrays from prefetched dt
                const int g = tid >> 6;
                const int t2 = lane;
                float e = __expf(pfd);
                float dts = __logf(1.f + e);               // softplus
                float s = dts;
                #pragma unroll
                for (int off = 1; off < 64; off <<= 1) {   // inclusive prefix sum
                    float v = __shfl_up(s, off, 64);
                    if (lane >= off) s += v;
                }
                float stot = __shfl(s, 63, 64);
                float smid = __shfl(s, 31, 64);            // mid-centering (overflow-safe)
                Warr[g][t2]  = __expf(s - stot) * dts;     // H-ingest weight
                Earr[g][t2]  = __expf(-s);                 // chunk decay / C scale
                Wmarr[g][t2] = __expf(s - smid) * dts;     // mask col factor
                Rmarr[g][t2] = __expf(smid - s);           // mask row factor
            }
        }
        // issue prefetch for chunk c+1 (stays in flight across all barriers)
        if (c != 15) {
            pRow += dRow; pC += dRow; pDt += dDt;
            pfx0 = *(const bf16x8*)(pRow + xoff);
            pfx1 = *(const bf16x8*)(pRow + xoff + 8);
            pfbA0 = *(const bf16x8*)(pRow + 1536 + scol);
            pfbA1 = *(const bf16x8*)(pRow + 1536 + scol + 8);
            pfbB0 = *(const bf16x8*)(pRow + 1600 + scol);
            pfbB1 = *(const bf16x8*)(pRow + 1600 + scol + 8);
            pfc00 = *(const bf16x8*)(pC + fkq);
            pfc01 = *(const bf16x8*)(pC + 32 + fkq);
            pfc10 = *(const bf16x8*)(pC + 64 + fkq);
            pfc11 = *(const bf16x8*)(pC + 96 + fkq);
            if (tid < 128) pfd = *pDt;
        }
        bar_lds();   // (a) XT/scan-arrays ready

        f32x4 Yacc[4] = {};

        auto group = [&](const int g, f32x4 (&Hst)[4],
                         bf16x8 bR0, bf16x8 bR1, bf16x8 cf0, bf16x8 cf1) {
            {   // stage Ts (scattered, w-scaled) + Bss (vector, swizzled) from B-row regs
                const float ws = Warr[g][sl];
                const int rsw = (sl & 7) << 3;
                #pragma unroll
                for (int i = 0; i < 8; ++i) {
                    const int n = scol + i;
                    Ts[n*PADW + (sl ^ (((n >> 3) & 7) << 3))] = (__bf16)((float)bR0[i] * ws);
                }
                #pragma unroll
                for (int i = 0; i < 8; ++i) {
                    const int n = scol + 8 + i;
                    Ts[n*PADW + (sl ^ (((n >> 3) & 7) << 3))] = (__bf16)((float)bR1[i] * ws);
                }
                *(bf16x8*)&Bss[sl*64 + (scol ^ rsw)] = bR0;
                *(bf16x8*)&Bss[sl*64 + ((scol + 8) ^ rsw)] = bR1;
            }
            // write H^T (h_init, unscaled) from regs, packed bf16x2
            #pragma unroll
            for (int t4 = 0; t4 < 4; ++t4) {
                const int p = t4*16 + ec;
                #pragma unroll
                for (int j = 0; j < 2; ++j) {
                    const int n = w*16 + er + 2*j;
                    __hip_bfloat162 pr;
                    pr.x = __float2bfloat16(Hst[t4][2*j]);
                    pr.y = __float2bfloat16(Hst[t4][2*j+1]);
                    *(__hip_bfloat162*)&HT[p*PADW + n] = pr;
                }
            }
            bar_lds();   // (c) Ts/Bss/HT ready
            // G = C B^T (K = n = 64), B frags from LDS
            f32x4 Gacc[4] = {};
            __builtin_amdgcn_s_setprio(1);
            #pragma unroll
            for (int s4 = 0; s4 < 4; ++s4) {
                const int s = s4*16 + fr;
                const int ssw = (s & 7) << 3;
                bf16x8 bb0 = *(const bf16x8*)&Bss[s*64 + (fkq ^ ssw)];
                bf16x8 bb1 = *(const bf16x8*)&Bss[s*64 + ((32 + fkq) ^ ssw)];
                Gacc[s4] = mfma16(cf0, bb0, Gacc[s4]);
                Gacc[s4] = mfma16(cf1, bb1, Gacc[s4]);
            }
            __builtin_amdgcn_s_setprio(0);
            // scale H regs by chunk decay
            const float e63 = Earr[g][63];
            #pragma unroll
            for (int t4 = 0; t4 < 4; ++t4)
                #pragma unroll
                for (int rr = 0; rr < 4; ++rr) Hst[t4][rr] *= e63;
            // mask G -> Gs: m = Wm[s] * Rm[tau] (no exp; factored, mid-centered)
            float rmv[4];
            #pragma unroll
            for (int rr = 0; rr < 4; ++rr) rmv[rr] = Rmarr[g][w*16 + er + rr];
            #pragma unroll
            for (int s4 = 0; s4 < 4; ++s4) {
                const int s = s4*16 + ec;
                const float wm = Wmarr[g][s];
                #pragma unroll
                for (int rr = 0; rr < 4; ++rr) {
                    const int tau = w*16 + er + rr;
                    float m = (tau >= s) ? wm * rmv[rr] : 0.f;
                    Gs[tau*PADW + s] = (__bf16)(Gacc[s4][rr] * m);
                }
            }
            // Y += G' X + (E*C) H ; H += (wB)^T X
            bf16x8 ga0 = *(const bf16x8*)&Gs[rn*PADW + fkq];
            bf16x8 ga1 = *(const bf16x8*)&Gs[rn*PADW + 32 + fkq];
            const float esc = Earr[g][rn];
            bf16x8 ca0, ca1;
            #pragma unroll
            for (int i = 0; i < 8; ++i) {
                ca0[i] = (__bf16)((float)cf0[i] * esc);
                ca1[i] = (__bf16)((float)cf1[i] * esc);
            }
            const int Sn = ((rn >> 3) & 7) << 3;
            bf16x8 ta0 = *(const bf16x8*)&Ts[rn*PADW + (fkq ^ Sn)];
            bf16x8 ta1 = *(const bf16x8*)&Ts[rn*PADW + ((32 + fkq) ^ Sn)];
            __builtin_amdgcn_s_setprio(1);
            #pragma unroll
            for (int p4 = 0; p4 < 4; ++p4) {
                const int p = p4*16 + fr;
                const int Sp = ((p >> 3) & 7) << 3;
                bf16x8 x0 = *(const bf16x8*)&XT[p*PADW + (fkq ^ Sp)];
                bf16x8 x1 = *(const bf16x8*)&XT[p*PADW + ((32 + fkq) ^ Sp)];
                bf16x8 h0 = *(const bf16x8*)&HT[p*PADW + fkq];
                bf16x8 h1 = *(const bf16x8*)&HT[p*PADW + 32 + fkq];
                Yacc[p4] = mfma16(ga0, x0, Yacc[p4]);
                Yacc[p4] = mfma16(ga1, x1, Yacc[p4]);
                Yacc[p4] = mfma16(ca0, h0, Yacc[p4]);
                Yacc[p4] = mfma16(ca1, h1, Yacc[p4]);
                Hst[p4] = mfma16(ta0, x0, Hst[p4]);
                Hst[p4] = mfma16(ta1, x1, Hst[p4]);
            }
            __builtin_amdgcn_s_setprio(0);
        };

        group(0, Hst0, bA0, bA1, c00, c01);
        bar_lds();   // WAR: g1's Ts/Bss/HT writes vs g0's reads
        group(1, Hst1, bB0, bB1, c10, c11);

        // y-stage into Gs (wave-private rows; own ga reads already retired in order)
        #pragma unroll
        for (int p4 = 0; p4 < 4; ++p4)
            #pragma unroll
            for (int rr = 0; rr < 4; ++rr) {
                const int tau = w*16 + er + rr;
                Gs[tau*PADW + p4*16 + ec] = (__bf16)Yacc[p4][rr];
            }
        bar_lds();   // (y)
        {   // coalesced y store, [h][row][64] layout: full-line streaming
            const int rowp = rA + (dir ? 63 - srow : srow);
            bf16x8 y0 = *(const bf16x8*)&Gs[srow*PADW + scol];
            bf16x8 y1 = *(const bf16x8*)&Gs[srow*PADW + scol + 8];
            __bf16* dst = yout + ((size_t)h * Rtot + (base + rowp)) * 64 + scol;
            *(bf16x8*)dst = y0;
            *(bf16x8*)(dst + 8) = y1;
        }
    }
}

// ---------------- gate (y * silu(z)) + RMSNorm + norm_w, bf16 out ----------------
// yf/yr are in [h][row][64] layout (h = j>>6 for feature index j).
__global__ __launch_bounds__(256) void gate_kernel(
    const __hip_bfloat16* __restrict__ yf, const __hip_bfloat16* __restrict__ yr,
    const __hip_bfloat16* __restrict__ z, const float* __restrict__ norm_w,
    __hip_bfloat16* __restrict__ yn)
{
    const int row = blockIdx.x, tid = threadIdx.x;
    const size_t R = gridDim.x;
    const size_t ybase = (size_t)row * D_INNER;
    float yg[6]; float ss = 0.f;
    #pragma unroll
    for (int k = 0; k < 6; ++k) {
        int j = tid + k*256;
        size_t yidx = ((size_t)(j >> 6) * R + row) * 64 + (j & 63);
        float yv = __bfloat162float(yf[yidx]) + __bfloat162float(yr[yidx]);
        float zz = __bfloat162float(z[ybase+j]);
        float g  = yv * (zz / (1.f + __expf(-zz)));
        yg[k] = g; ss += g*g;
    }
    #pragma unroll
    for (int off = 32; off > 0; off >>= 1) ss += __shfl_down(ss, off, 64);
    __shared__ float red[4];
    if ((tid & 63) == 0) red[tid >> 6] = ss;
    __syncthreads();
    float total = red[0] + red[1] + red[2] + red[3];
    float rn = rsqrtf(total * (1.f/1536.f) + 1e-5f);
    #pragma unroll
    for (int k = 0; k < 6; ++k) {
        int j = tid + k*256;
        yn[ybase+j] = __float2bfloat16(yg[k] * rn * norm_w[j]);
    }
}

// ---------------- launch ----------------
extern "C" void kernel_launch(void* const* d_in, const int* in_sizes, int n_in,
                              void* d_out, int out_size, void* d_ws, size_t ws_size,
                              hipStream_t stream) {
    const float* u      = (const float*)d_in[0];
    const float* w_in   = (const float*)d_in[1];
    const float* conv_w = (const float*)d_in[2];
    const float* conv_b = (const float*)d_in[3];
    const float* norm_w = (const float*)d_in[4];
    const float* w_out  = (const float*)d_in[5];
    (void)in_sizes; (void)n_in; (void)out_size;

    char* ws = (char*)d_ws;
    const size_t nWin  = (size_t)D_IN_PROJ * D_MODEL;
    const size_t nWout = (size_t)D_MODEL * D_INNER;
    __hip_bfloat16* win_bf  = (__hip_bfloat16*)ws;
    __hip_bfloat16* wout_bf = (__hip_bfloat16*)(ws + nWin*2);
    float* wT = (float*)(ws + nWin*2 + nWout*2);
    const size_t wbytes = nWin*2 + nWout*2 + (size_t)9*CONV_DIM*4;
    char* arena = ws + wbytes;

    const size_t perRow = 10624;
    int CB = 32;
    while (CB > 1 && wbytes + perRow*(size_t)CB*1024 > ws_size) CB >>= 1;
    const int nchunks = 32 / CB;
    const size_t R = (size_t)CB * 1024;

    __hip_bfloat16* segA = (__hip_bfloat16*)arena;                 // u_bf, then yf
    char* pC = arena + R*3072;
    char* pD = pC + R*3584;
    char* pE = pD + R*384;
    __hip_bfloat16* xbc_bf  = (__hip_bfloat16*)pC;                 // then yr
    __hip_bfloat16* yr_bf   = (__hip_bfloat16*)pC;
    float*          dt_f32  = (float*)pD;
    __hip_bfloat16* conv_bf = (__hip_bfloat16*)pE;                 // then yn
    __hip_bfloat16* yn_bf   = (__hip_bfloat16*)pE;
    __hip_bfloat16* u_bf    = segA;
    __hip_bfloat16* yf_bf   = segA;

    cvt_kernel<<<(int)((nWin/4 + 255)/256), 256, 0, stream>>>(w_in, win_bf, (int)(nWin/4));
    cvt_kernel<<<(int)((nWout/4 + 255)/256), 256, 0, stream>>>(w_out, wout_bf, (int)(nWout/4));
    repack_w<<<(CONV_DIM*9 + 255)/256, 256, 0, stream>>>(conv_w, wT);

    for (int c = 0; c < nchunks; ++c) {
        const float* u_c = u + (size_t)c * R * D_MODEL;
        __hip_bfloat16* z_bf = (__hip_bfloat16*)((char*)d_out + (size_t)c * R * 3072);
        float* out_c = (float*)d_out + (size_t)c * R * D_MODEL;

        const size_t nUc4 = R * D_MODEL / 4;
        cvt_kernel<<<(int)((nUc4 + 255)/256), 256, 0, stream>>>(u_c, u_bf, (int)nUc4);

        gemm_bt<1><<<dim3((int)(R/128), (D_IN_PROJ + 127)/128), 256, 0, stream>>>(
            u_bf, win_bf, nullptr, z_bf, xbc_bf, dt_f32, (int)R, D_IN_PROJ, D_MODEL);

        conv_kernel<<<(int)((R*(CONV_DIM/8))/256), 256, 0, stream>>>(xbc_bf, wT, conv_b, conv_bf);

        scan_ssd<<<dim3(CB, NH, 2), 256, 0, stream>>>(
            (const __bf16*)conv_bf, dt_f32, (__bf16*)yf_bf, (__bf16*)yr_bf);

        gate_kernel<<<(int)R, 256, 0, stream>>>(yf_bf, yr_bf, z_bf, norm_w, yn_bf);

        gemm_bt<0><<<dim3((int)(R/128), D_MODEL/128), 256, 0, stream>>>(
            yn_bf, wout_bf, out_c, nullptr, nullptr, nullptr, (int)R, D_MODEL, D_INNER);
    }
}

// Round 7
// 1040.262 us; speedup vs baseline: 1.7566x; 1.1093x over previous
//
#include <hip/hip_runtime.h>
#include <hip/hip_bf16.h>
#include <stdint.h>

// ChimeraBlock (Mamba2-style) for MI355X.
// Round 11 = Round 10 + prefetch-register lifetime fix:
//   BUG in r10: cf[][] (C fragments) was built from pfc00..pfc11 AFTER the
//   next-chunk prefetch overwrote them -> chunks 0..14 used chunk c+1's C.
//   FIX: snapshot c00..c11 before the prefetch reissue (as r9 did).
// Structure (from r10):
//   - 2 barriers/chunk; per-group LDS double-buffered (Ts/Bss/HT x2)
//   - scan arrays computed one chunk ahead (parity dbuf) by tid<128 crew
//   - merged MFMA clusters (16 G + 48 Y/H); single f32 Yacc both groups
//   - stride-64 buffers, XOR swizzle SW(r); LDS 68KB -> 2 blocks/CU
//   - lgkmcnt-only barriers, full-chunk register prefetch, setprio on MFMA

#define D_MODEL 768
#define D_INNER 1536
#define NH 24
#define D_IN_PROJ 3424      // 2*1536 + 256 + 96
#define CONV_DIM 1792       // 1536 + 256
#define NDT 96
#define LSEQ 1024

typedef __bf16 bf16x8 __attribute__((ext_vector_type(8)));
typedef float f32x4 __attribute__((ext_vector_type(4)));

// ---------------- f32 -> bf16 convert (x4 vectorized) ----------------
__global__ void cvt_kernel(const float* __restrict__ src, __hip_bfloat16* __restrict__ dst, int n4) {
    int i = blockIdx.x * 256 + threadIdx.x;
    if (i < n4) {
        float4 v = ((const float4*)src)[i];
        __hip_bfloat162 lo, hi;
        lo.x = __float2bfloat16(v.x); lo.y = __float2bfloat16(v.y);
        hi.x = __float2bfloat16(v.z); hi.y = __float2bfloat16(v.w);
        ((__hip_bfloat162*)dst)[2*i]   = lo;
        ((__hip_bfloat162*)dst)[2*i+1] = hi;
    }
}

// ---------------- conv weight repack: (1792, 9) -> (9, 1792) ----------------
__global__ void repack_w(const float* __restrict__ cw, float* __restrict__ wT) {
    int i = blockIdx.x * 256 + threadIdx.x;
    if (i < CONV_DIM * 9) {
        int c = i / 9, t = i % 9;
        wT[t * CONV_DIM + c] = cw[i];
    }
}

// ---------------- bf16 NT GEMM: C[m,n] = sum_k A[m,k] * Bt[n,k] ----------------
__device__ __forceinline__ void gl_lds16(const __hip_bfloat16* g, __hip_bfloat16* l) {
    __builtin_amdgcn_global_load_lds(
        (const __attribute__((address_space(1))) void*)g,
        (__attribute__((address_space(3))) void*)l, 16, 0, 0);
}

// MODE 0: f32 out (OutF, width N).  MODE 1: split out -> Z(1536) | XBC(1792) | DT(96 f32)
template<int MODE>
__global__ __launch_bounds__(256) void gemm_bt(
    const __hip_bfloat16* __restrict__ A,   // M x K
    const __hip_bfloat16* __restrict__ Bt,  // N x K
    float* __restrict__ OutF,
    __hip_bfloat16* __restrict__ Z, __hip_bfloat16* __restrict__ XBC, float* __restrict__ DT,
    int M, int N, int K)
{
    __shared__ __hip_bfloat16 As[128*32];
    __shared__ __hip_bfloat16 Bs[128*32];
    const int tid  = threadIdx.x;
    const int wave = tid >> 6, lane = tid & 63;
    const int bm = blockIdx.x * 128, bn = blockIdx.y * 128;
    const int wm = (wave >> 1) * 64, wn = (wave & 1) * 64;
    f32x4 acc[4][4] = {};
    const int lrow = lane >> 2;
    const int lcol = (lane & 3) * 8;
    const int fr = lane & 15, fk = (lane >> 4) * 8;
    const int ktiles = K >> 5;
    for (int kt = 0; kt < ktiles; ++kt) {
        const int kofs = kt * 32;
        #pragma unroll
        for (int cc = 0; cc < 2; ++cc) {
            int r = (wave*2 + cc)*16 + lrow;
            gl_lds16(A + (size_t)(bm + r)*K + kofs + lcol, &As[r*32 + lcol]);
            int gn = bn + r; if (gn > N-1) gn = N-1;
            gl_lds16(Bt + (size_t)gn*K + kofs + lcol, &Bs[r*32 + lcol]);
        }
        __syncthreads();
        bf16x8 af[4], bfr[4];
        #pragma unroll
        for (int i = 0; i < 4; ++i)
            af[i] = *reinterpret_cast<const bf16x8*>(&As[(wm + i*16 + fr)*32 + fk]);
        #pragma unroll
        for (int j = 0; j < 4; ++j)
            bfr[j] = *reinterpret_cast<const bf16x8*>(&Bs[(wn + j*16 + fr)*32 + fk]);
        #pragma unroll
        for (int i = 0; i < 4; ++i)
            #pragma unroll
            for (int j = 0; j < 4; ++j)
                acc[i][j] = __builtin_amdgcn_mfma_f32_16x16x32_bf16(af[i], bfr[j], acc[i][j], 0, 0, 0);
        __syncthreads();
    }
    const int er = (lane >> 4) * 4;
    const int ec = lane & 15;
    #pragma unroll
    for (int i = 0; i < 4; ++i) {
        #pragma unroll
        for (int j = 0; j < 4; ++j) {
            #pragma unroll
            for (int r = 0; r < 4; ++r) {
                int row = bm + wm + i*16 + er + r;
                int col = bn + wn + j*16 + ec;
                if (col < N) {
                    float v = acc[i][j][r];
                    if (MODE == 0) {
                        OutF[(size_t)row*N + col] = v;
                    } else {
                        if (col < D_INNER)
                            Z[(size_t)row*D_INNER + col] = __float2bfloat16(v);
                        else if (col < 3328)
                            XBC[(size_t)row*CONV_DIM + (col - D_INNER)] = __float2bfloat16(v);
                        else
                            DT[(size_t)row*NDT + (col - 3328)] = v;
                    }
                }
            }
        }
    }
}

// ---------------- depthwise 3x3 conv + bias + SiLU, 8 ch/thread ----------------
__global__ __launch_bounds__(256) void conv_kernel(
    const __hip_bfloat16* __restrict__ xbc, // (R, 1792)
    const float* __restrict__ wT,           // (9, 1792) repacked
    const float* __restrict__ cb,           // (1792)
    __hip_bfloat16* __restrict__ out)       // (R, 1792)
{
    size_t idx = (size_t)blockIdx.x * 256 + threadIdx.x;   // R * 224 threads
    const int cg = (int)(idx % (CONV_DIM / 8));
    const int c = cg * 8;
    size_t bp = idx / (CONV_DIM / 8);
    const int pix = (int)(bp % LSEQ);
    const int b = (int)(bp / LSEQ);
    const int y = pix >> 5, x = pix & 31;
    float acc[8];
    {
        float4 c0 = *(const float4*)(cb + c);
        float4 c1 = *(const float4*)(cb + c + 4);
        acc[0]=c0.x; acc[1]=c0.y; acc[2]=c0.z; acc[3]=c0.w;
        acc[4]=c1.x; acc[5]=c1.y; acc[6]=c1.z; acc[7]=c1.w;
    }
    const size_t rowbase = (size_t)b * LSEQ;
    #pragma unroll
    for (int dy = -1; dy <= 1; ++dy) {
        int yy = y + dy; if (yy < 0 || yy > 31) continue;
        #pragma unroll
        for (int dx = -1; dx <= 1; ++dx) {
            int xx = x + dx; if (xx < 0 || xx > 31) continue;
            const int t = (dy+1)*3 + (dx+1);
            bf16x8 v = *(const bf16x8*)(xbc + (rowbase + yy*32 + xx)*(size_t)CONV_DIM + c);
            float4 w0 = *(const float4*)(wT + t*CONV_DIM + c);
            float4 w1 = *(const float4*)(wT + t*CONV_DIM + c + 4);
            acc[0] += w0.x * (float)v[0];
            acc[1] += w0.y * (float)v[1];
            acc[2] += w0.z * (float)v[2];
            acc[3] += w0.w * (float)v[3];
            acc[4] += w1.x * (float)v[4];
            acc[5] += w1.y * (float)v[5];
            acc[6] += w1.z * (float)v[6];
            acc[7] += w1.w * (float)v[7];
        }
    }
    bf16x8 o;
    #pragma unroll
    for (int i = 0; i < 8; ++i) {
        float s = acc[i] / (1.f + __expf(-acc[i]));
        o[i] = (__bf16)s;
    }
    *(bf16x8*)(out + (rowbase + pix)*(size_t)CONV_DIM + c) = o;
}

// ---------------- chunked SSD scan on MFMA ----------------
// Row-XOR column swizzle for stride-64 bf16 LDS rows: conflict-free b128 reads
// when 16 lanes read consecutive rows at the same column group.
#define SW(r) ((((r) & 7) ^ (((r) >> 3) & 7)) << 3)
__device__ __forceinline__ f32x4 mfma16(bf16x8 a, bf16x8 b, f32x4 c) {
    return __builtin_amdgcn_mfma_f32_16x16x32_bf16(a, b, c, 0, 0, 0);
}
// LDS-only barrier: waits own LDS ops (lgkmcnt), does NOT drain vmcnt, and
// pins post-barrier code behind the barrier (sched_barrier).
__device__ __forceinline__ void bar_lds() {
    asm volatile("s_waitcnt lgkmcnt(0)" ::: "memory");
    __builtin_amdgcn_s_barrier();
    __builtin_amdgcn_sched_barrier(0);
}

__global__ __launch_bounds__(256, 2) void scan_ssd(
    const __bf16* __restrict__ conv,   // (R, 1792): x | B(2x64) | C(2x64)
    const float* __restrict__ dtraw,   // (R, 96): [k][h], k = 2g + dir
    __bf16* __restrict__ yf,           // (NH, R, 64)
    __bf16* __restrict__ yr)           // (NH, R, 64)
{
    const int tid = threadIdx.x;
    const int w = tid >> 6, lane = tid & 63;
    const int b = blockIdx.x, h = blockIdx.y, dir = blockIdx.z;
    __bf16* yout = dir ? yr : yf;
    const size_t base = (size_t)b * LSEQ;
    const size_t Rtot = (size_t)gridDim.x * LSEQ;

    __shared__ __align__(16) __bf16 XT[64*64];      // [p][tau ^ SW(p)]
    __shared__ __align__(16) __bf16 Gs[64*64];      // [tau][s ^ SW(tau)]; reused per group + y-stage
    __shared__ __align__(16) __bf16 Ts[2][64*64];   // [n][s ^ SW(n)]  (w-scaled B^T)
    __shared__ __align__(16) __bf16 Bss[2][64*64];  // [s][n ^ SW(s)]
    __shared__ __align__(16) __bf16 HT[2][64*64];   // [p][n ^ SW(p)]
    __shared__ float Warr[2][2][64], Earr[2][2][64], Wmarr[2][2][64], Rmarr[2][2][64];

    f32x4 Hst0[4] = {}, Hst1[4] = {};      // H_g[n][p]: n-slab = wave (16 rows), per group

    const int srow = tid >> 2;             // staging: physical row offset 0..63
    const int scol = (tid & 3) * 16;       // staging: 16-element column group
    const int fr = lane & 15, fkq = (lane >> 4) * 8;   // frag row / k base
    const int er = (lane >> 4) * 4, ec = lane & 15;    // C/D row base / col
    const int rn = w*16 + fr;
    const int sl = dir ? 63 - srow : srow; // logical scan index of staged row
    const int swsl = SW(sl);
    const int swrn = SW(rn);

    // ---- per-chunk-stepped global pointers ----
    const int rA0 = dir ? (LSEQ - 64) : 0;
    const ptrdiff_t dRow = (ptrdiff_t)(dir ? -64 : 64) * CONV_DIM;
    const ptrdiff_t dDt  = (ptrdiff_t)(dir ? -64 : 64) * NDT;
    const __bf16* pRow = conv + (base + rA0 + srow) * (size_t)CONV_DIM;       // staging row
    const __bf16* pC   = conv + (base + rA0 + (dir ? 63 - rn : rn)) * (size_t)CONV_DIM + 1664;
    const float*  pDt  = dtraw + (base + rA0 + (dir ? 63 - lane : lane)) * NDT
                         + (2*(tid >> 6) + dir)*24 + h;                       // valid for tid<128
    const int xoff = h*64 + scol;

    // ---- prologue: scan arrays for chunk 0 + prefetch chunk 0 + dt chunk 1 ----
    float pfdN = 0.f;
    if (tid < 128) {
        const int g = tid >> 6;
        float d0 = *pDt;
        float e = __expf(d0);
        float dts = __logf(1.f + e);
        float s = dts;
        #pragma unroll
        for (int off = 1; off < 64; off <<= 1) {
            float v = __shfl_up(s, off, 64);
            if (lane >= off) s += v;
        }
        float stot = __shfl(s, 63, 64);
        float smid = __shfl(s, 31, 64);
        Warr[0][g][lane]  = __expf(s - stot) * dts;
        Earr[0][g][lane]  = __expf(-s);
        Wmarr[0][g][lane] = __expf(s - smid) * dts;
        Rmarr[0][g][lane] = __expf(smid - s);
        pDt += dDt;
        pfdN = *pDt;                       // dt for chunk 1 (in flight)
    }
    bf16x8 pfx0 = *(const bf16x8*)(pRow + xoff);
    bf16x8 pfx1 = *(const bf16x8*)(pRow + xoff + 8);
    bf16x8 pfb00 = *(const bf16x8*)(pRow + 1536 + scol);
    bf16x8 pfb01 = *(const bf16x8*)(pRow + 1536 + scol + 8);
    bf16x8 pfb10 = *(const bf16x8*)(pRow + 1600 + scol);
    bf16x8 pfb11 = *(const bf16x8*)(pRow + 1600 + scol + 8);
    bf16x8 pfc00 = *(const bf16x8*)(pC + fkq);
    bf16x8 pfc01 = *(const bf16x8*)(pC + 32 + fkq);
    bf16x8 pfc10 = *(const bf16x8*)(pC + 64 + fkq);
    bf16x8 pfc11 = *(const bf16x8*)(pC + 96 + fkq);
    bar_lds();   // publish arrays[0]

    #pragma unroll 1
    for (int c = 0; c < 16; ++c) {
        const int cb = c & 1;
        const int rA = dir ? (LSEQ - (c+1)*64) : c*64;   // physical start row

        // SNAPSHOT this chunk's C frags BEFORE the prefetch reissue clobbers
        // pfc* (r10 bug: cf[] built from pfc* after reissue -> next chunk's C).
        const bf16x8 c00 = pfc00, c01 = pfc01, c10 = pfc10, c11 = pfc11;

        // ---- staging phase (one barrier later covers everything) ----
        {   // XT scatter-transpose
            #pragma unroll
            for (int i = 0; i < 8; ++i) {
                const int p = scol + i;
                XT[p*64 + (sl ^ SW(p))] = pfx0[i];
            }
            #pragma unroll
            for (int i = 0; i < 8; ++i) {
                const int p = scol + 8 + i;
                XT[p*64 + (sl ^ SW(p))] = pfx1[i];
            }
        }
        {   // Ts + Bss for both groups (w-scale from arrays[cb], published)
            const float ws0 = Warr[cb][0][sl];
            const float ws1 = Warr[cb][1][sl];
            #pragma unroll
            for (int i = 0; i < 8; ++i) {
                const int n = scol + i;
                Ts[0][n*64 + (sl ^ SW(n))] = (__bf16)((float)pfb00[i] * ws0);
                Ts[1][n*64 + (sl ^ SW(n))] = (__bf16)((float)pfb10[i] * ws1);
            }
            #pragma unroll
            for (int i = 0; i < 8; ++i) {
                const int n = scol + 8 + i;
                Ts[0][n*64 + (sl ^ SW(n))] = (__bf16)((float)pfb01[i] * ws0);
                Ts[1][n*64 + (sl ^ SW(n))] = (__bf16)((float)pfb11[i] * ws1);
            }
            *(bf16x8*)&Bss[0][sl*64 + (scol ^ swsl)]       = pfb00;
            *(bf16x8*)&Bss[0][sl*64 + ((scol + 8) ^ swsl)] = pfb01;
            *(bf16x8*)&Bss[1][sl*64 + (scol ^ swsl)]       = pfb10;
            *(bf16x8*)&Bss[1][sl*64 + ((scol + 8) ^ swsl)] = pfb11;
        }
        {   // HT for both groups from H regs (h_init, unscaled), packed bf16x2
            #pragma unroll
            for (int t4 = 0; t4 < 4; ++t4) {
                const int p = t4*16 + ec;
                const int swp = SW(p);
                #pragma unroll
                for (int j = 0; j < 2; ++j) {
                    const int n = w*16 + er + 2*j;
                    __hip_bfloat162 pr0, pr1;
                    pr0.x = __float2bfloat16(Hst0[t4][2*j]);
                    pr0.y = __float2bfloat16(Hst0[t4][2*j+1]);
                    pr1.x = __float2bfloat16(Hst1[t4][2*j]);
                    pr1.y = __float2bfloat16(Hst1[t4][2*j+1]);
                    *(__hip_bfloat162*)&HT[0][p*64 + (n ^ swp)] = pr0;
                    *(__hip_bfloat162*)&HT[1][p*64 + (n ^ swp)] = pr1;
                }
            }
        }
        // scale H regs by chunk decay (arrays[cb] already published)
        {
            const float e630 = Earr[cb][0][63];
            const float e631 = Earr[cb][1][63];
            #pragma unroll
            for (int t4 = 0; t4 < 4; ++t4)
                #pragma unroll
                for (int rr = 0; rr < 4; ++rr) {
                    Hst0[t4][rr] *= e630;
                    Hst1[t4][rr] *= e631;
                }
        }
        // crew: scan arrays for chunk c+1 from in-flight dt (no stall; pfdN arrived)
        if (c < 15 && tid < 128) {
            const int g = tid >> 6;
            float e = __expf(pfdN);
            float dts = __logf(1.f + e);
            float s = dts;
            #pragma unroll
            for (int off = 1; off < 64; off <<= 1) {
                float v = __shfl_up(s, off, 64);
                if (lane >= off) s += v;
            }
            float stot = __shfl(s, 63, 64);
            float smid = __shfl(s, 31, 64);
            const int nb = cb ^ 1;
            Warr[nb][g][lane]  = __expf(s - stot) * dts;
            Earr[nb][g][lane]  = __expf(-s);
            Wmarr[nb][g][lane] = __expf(s - smid) * dts;
            Rmarr[nb][g][lane] = __expf(smid - s);
        }
        // issue prefetch for chunk c+1 (stays in flight across barriers)
        if (c != 15) {
            pRow += dRow; pC += dRow;
            pfx0 = *(const bf16x8*)(pRow + xoff);
            pfx1 = *(const bf16x8*)(pRow + xoff + 8);
            pfb00 = *(const bf16x8*)(pRow + 1536 + scol);
            pfb01 = *(const bf16x8*)(pRow + 1536 + scol + 8);
            pfb10 = *(const bf16x8*)(pRow + 1600 + scol);
            pfb11 = *(const bf16x8*)(pRow + 1600 + scol + 8);
            pfc00 = *(const bf16x8*)(pC + fkq);
            pfc01 = *(const bf16x8*)(pC + 32 + fkq);
            pfc10 = *(const bf16x8*)(pC + 64 + fkq);
            pfc11 = *(const bf16x8*)(pC + 96 + fkq);
            if (c < 14 && tid < 128) { pDt += dDt; pfdN = *pDt; }   // dt for c+2
        }
        bar_lds();   // (a) all staging visible

        // ---- compute phase: G + mask + frags for both groups, then Y/H mega ----
        bf16x8 cf[2][2] = { { c00, c01 }, { c10, c11 } };
        bf16x8 ga[2][2], ca[2][2], ta[2][2];
        #pragma unroll
        for (int g = 0; g < 2; ++g) {
            f32x4 Gacc[4] = {};
            __builtin_amdgcn_s_setprio(1);
            #pragma unroll
            for (int s4 = 0; s4 < 4; ++s4) {
                const int s = s4*16 + fr;
                const int ss = SW(s);
                bf16x8 bb0 = *(const bf16x8*)&Bss[g][s*64 + (fkq ^ ss)];
                bf16x8 bb1 = *(const bf16x8*)&Bss[g][s*64 + ((32 + fkq) ^ ss)];
                Gacc[s4] = mfma16(cf[g][0], bb0, Gacc[s4]);
                Gacc[s4] = mfma16(cf[g][1], bb1, Gacc[s4]);
            }
            __builtin_amdgcn_s_setprio(0);
            // mask -> Gs (wave-own rows): m = Wm[s] * Rm[tau]
            float rmv[4];
            #pragma unroll
            for (int rr = 0; rr < 4; ++rr) rmv[rr] = Rmarr[cb][g][w*16 + er + rr];
            #pragma unroll
            for (int s4 = 0; s4 < 4; ++s4) {
                const int s = s4*16 + ec;
                const float wm = Wmarr[cb][g][s];
                #pragma unroll
                for (int rr = 0; rr < 4; ++rr) {
                    const int tau = w*16 + er + rr;
                    float m = (tau >= s) ? wm * rmv[rr] : 0.f;
                    Gs[tau*64 + (s ^ SW(tau))] = (__bf16)(Gacc[s4][rr] * m);
                }
            }
            // frags (wave-own rows; LDS ops in-order per wave)
            ga[g][0] = *(const bf16x8*)&Gs[rn*64 + (fkq ^ swrn)];
            ga[g][1] = *(const bf16x8*)&Gs[rn*64 + ((32 + fkq) ^ swrn)];
            const float esc = Earr[cb][g][rn];
            #pragma unroll
            for (int i = 0; i < 8; ++i) {
                ca[g][0][i] = (__bf16)((float)cf[g][0][i] * esc);
                ca[g][1][i] = (__bf16)((float)cf[g][1][i] * esc);
            }
            ta[g][0] = *(const bf16x8*)&Ts[g][rn*64 + (fkq ^ swrn)];
            ta[g][1] = *(const bf16x8*)&Ts[g][rn*64 + ((32 + fkq) ^ swrn)];
        }
        // Y = G'X + (EC)H0 + (EC)H1 ; H_g += (wB)^T X
        f32x4 Yacc[4] = {};
        __builtin_amdgcn_s_setprio(1);
        #pragma unroll
        for (int p4 = 0; p4 < 4; ++p4) {
            const int p = p4*16 + fr;
            const int sp = SW(p);
            bf16x8 x0  = *(const bf16x8*)&XT[p*64 + (fkq ^ sp)];
            bf16x8 x1  = *(const bf16x8*)&XT[p*64 + ((32 + fkq) ^ sp)];
            bf16x8 h00 = *(const bf16x8*)&HT[0][p*64 + (fkq ^ sp)];
            bf16x8 h01 = *(const bf16x8*)&HT[0][p*64 + ((32 + fkq) ^ sp)];
            bf16x8 h10 = *(const bf16x8*)&HT[1][p*64 + (fkq ^ sp)];
            bf16x8 h11 = *(const bf16x8*)&HT[1][p*64 + ((32 + fkq) ^ sp)];
            Yacc[p4] = mfma16(ga[0][0], x0, Yacc[p4]);
            Yacc[p4] = mfma16(ga[0][1], x1, Yacc[p4]);
            Yacc[p4] = mfma16(ca[0][0], h00, Yacc[p4]);
            Yacc[p4] = mfma16(ca[0][1], h01, Yacc[p4]);
            Yacc[p4] = mfma16(ga[1][0], x0, Yacc[p4]);
            Yacc[p4] = mfma16(ga[1][1], x1, Yacc[p4]);
            Yacc[p4] = mfma16(ca[1][0], h10, Yacc[p4]);
            Yacc[p4] = mfma16(ca[1][1], h11, Yacc[p4]);
            Hst0[p4] = mfma16(ta[0][0], x0, Hst0[p4]);
            Hst0[p4] = mfma16(ta[0][1], x1, Hst0[p4]);
            Hst1[p4] = mfma16(ta[1][0], x0, Hst1[p4]);
            Hst1[p4] = mfma16(ta[1][1], x1, Hst1[p4]);
        }
        __builtin_amdgcn_s_setprio(0);

        // y-stage into Gs (wave-own rows, overwrites after own ga reads)
        #pragma unroll
        for (int p4 = 0; p4 < 4; ++p4)
            #pragma unroll
            for (int rr = 0; rr < 4; ++rr) {
                const int tau = w*16 + er + rr;
                Gs[tau*64 + ((p4*16 + ec) ^ SW(tau))] = (__bf16)Yacc[p4][rr];
            }
        bar_lds();   // (y)
        {   // coalesced y store, [h][row][64] layout (store stays in flight)
            const int rowp = rA + (dir ? 63 - srow : srow);
            bf16x8 y0 = *(const bf16x8*)&Gs[srow*64 + (scol ^ SW(srow))];
            bf16x8 y1 = *(const bf16x8*)&Gs[srow*64 + ((scol + 8) ^ SW(srow))];
            __bf16* dst = yout + ((size_t)h * Rtot + (base + rowp)) * 64 + scol;
            *(bf16x8*)dst = y0;
            *(bf16x8*)(dst + 8) = y1;
        }
    }
}

// ---------------- gate (y * silu(z)) + RMSNorm + norm_w, bf16 out ----------------
// yf/yr are in [h][row][64] layout (h = j>>6 for feature index j).
__global__ __launch_bounds__(256) void gate_kernel(
    const __hip_bfloat16* __restrict__ yf, const __hip_bfloat16* __restrict__ yr,
    const __hip_bfloat16* __restrict__ z, const float* __restrict__ norm_w,
    __hip_bfloat16* __restrict__ yn)
{
    const int row = blockIdx.x, tid = threadIdx.x;
    const size_t R = gridDim.x;
    const size_t ybase = (size_t)row * D_INNER;
    float yg[6]; float ss = 0.f;
    #pragma unroll
    for (int k = 0; k < 6; ++k) {
        int j = tid + k*256;
        size_t yidx = ((size_t)(j >> 6) * R + row) * 64 + (j & 63);
        float yv = __bfloat162float(yf[yidx]) + __bfloat162float(yr[yidx]);
        float zz = __bfloat162float(z[ybase+j]);
        float g  = yv * (zz / (1.f + __expf(-zz)));
        yg[k] = g; ss += g*g;
    }
    #pragma unroll
    for (int off = 32; off > 0; off >>= 1) ss += __shfl_down(ss, off, 64);
    __shared__ float red[4];
    if ((tid & 63) == 0) red[tid >> 6] = ss;
    __syncthreads();
    float total = red[0] + red[1] + red[2] + red[3];
    float rn = rsqrtf(total * (1.f/1536.f) + 1e-5f);
    #pragma unroll
    for (int k = 0; k < 6; ++k) {
        int j = tid + k*256;
        yn[ybase+j] = __float2bfloat16(yg[k] * rn * norm_w[j]);
    }
}

// ---------------- launch ----------------
extern "C" void kernel_launch(void* const* d_in, const int* in_sizes, int n_in,
                              void* d_out, int out_size, void* d_ws, size_t ws_size,
                              hipStream_t stream) {
    const float* u      = (const float*)d_in[0];
    const float* w_in   = (const float*)d_in[1];
    const float* conv_w = (const float*)d_in[2];
    const float* conv_b = (const float*)d_in[3];
    const float* norm_w = (const float*)d_in[4];
    const float* w_out  = (const float*)d_in[5];
    (void)in_sizes; (void)n_in; (void)out_size;

    char* ws = (char*)d_ws;
    const size_t nWin  = (size_t)D_IN_PROJ * D_MODEL;
    const size_t nWout = (size_t)D_MODEL * D_INNER;
    __hip_bfloat16* win_bf  = (__hip_bfloat16*)ws;
    __hip_bfloat16* wout_bf = (__hip_bfloat16*)(ws + nWin*2);
    float* wT = (float*)(ws + nWin*2 + nWout*2);
    const size_t wbytes = nWin*2 + nWout*2 + (size_t)9*CONV_DIM*4;
    char* arena = ws + wbytes;

    const size_t perRow = 10624;
    int CB = 32;
    while (CB > 1 && wbytes + perRow*(size_t)CB*1024 > ws_size) CB >>= 1;
    const int nchunks = 32 / CB;
    const size_t R = (size_t)CB * 1024;

    __hip_bfloat16* segA = (__hip_bfloat16*)arena;                 // u_bf, then yf
    char* pC = arena + R*3072;
    char* pD = pC + R*3584;
    char* pE = pD + R*384;
    __hip_bfloat16* xbc_bf  = (__hip_bfloat16*)pC;                 // then yr
    __hip_bfloat16* yr_bf   = (__hip_bfloat16*)pC;
    float*          dt_f32  = (float*)pD;
    __hip_bfloat16* conv_bf = (__hip_bfloat16*)pE;                 // then yn
    __hip_bfloat16* yn_bf   = (__hip_bfloat16*)pE;
    __hip_bfloat16* u_bf    = segA;
    __hip_bfloat16* yf_bf   = segA;

    cvt_kernel<<<(int)((nWin/4 + 255)/256), 256, 0, stream>>>(w_in, win_bf, (int)(nWin/4));
    cvt_kernel<<<(int)((nWout/4 + 255)/256), 256, 0, stream>>>(w_out, wout_bf, (int)(nWout/4));
    repack_w<<<(CONV_DIM*9 + 255)/256, 256, 0, stream>>>(conv_w, wT);

    for (int c = 0; c < nchunks; ++c) {
        const float* u_c = u + (size_t)c * R * D_MODEL;
        __hip_bfloat16* z_bf = (__hip_bfloat16*)((char*)d_out + (size_t)c * R * 3072);
        float* out_c = (float*)d_out + (size_t)c * R * D_MODEL;

        const size_t nUc4 = R * D_MODEL / 4;
        cvt_kernel<<<(int)((nUc4 + 255)/256), 256, 0, stream>>>(u_c, u_bf, (int)nUc4);

        gemm_bt<1><<<dim3((int)(R/128), (D_IN_PROJ + 127)/128), 256, 0, stream>>>(
            u_bf, win_bf, nullptr, z_bf, xbc_bf, dt_f32, (int)R, D_IN_PROJ, D_MODEL);

        conv_kernel<<<(int)((R*(CONV_DIM/8))/256), 256, 0, stream>>>(xbc_bf, wT, conv_b, conv_bf);

        scan_ssd<<<dim3(CB, NH, 2), 256, 0, stream>>>(
            (const __bf16*)conv_bf, dt_f32, (__bf16*)yf_bf, (__bf16*)yr_bf);

        gate_kernel<<<(int)R, 256, 0, stream>>>(yf_bf, yr_bf, z_bf, norm_w, yn_bf);

        gemm_bt<0><<<dim3((int)(R/128), D_MODEL/128), 256, 0, stream>>>(
            yn_bf, wout_bf, out_c, nullptr, nullptr, nullptr, (int)R, D_MODEL, D_INNER);
    }
}